// Round 9
// baseline (764.099 us; speedup 1.0000x reference)
//
#include <hip/hip_runtime.h>
#include <hip/hip_bf16.h>
#include <math.h>

#define NCIRC 40000
#define NMI   15000
#define NDIS  8000
#define NTOT  (NCIRC + NMI + NDIS)
#define OFFSTR 40064

typedef __hip_bfloat16 bf16;
typedef __attribute__((ext_vector_type(8))) short short8;
typedef __attribute__((ext_vector_type(4))) float f32x4;
typedef __attribute__((ext_vector_type(8))) unsigned short us8v;

static __device__ __forceinline__ float us2f(unsigned short u){ return __uint_as_float(((unsigned)u) << 16); }
static __device__ __forceinline__ unsigned short f2bu(float v){
    bf16 t = __float2bfloat16(v);
    return *reinterpret_cast<unsigned short*>(&t);
}
static __device__ __forceinline__ float ldx(const void* p, size_t i, int f32){
    return f32 ? ((const float*)p)[i] : __bfloat162float(((const bf16*)p)[i]);
}
static inline unsigned cdiv(long long a, long long b){ return (unsigned)((a + b - 1) / b); }

// ---------- arg structs ----------
struct CsrArgs {
    const int* src[6]; const int* dst[6];
    int ecnt[6]; int eoff[6]; int nd[6];
};
struct Al1Args { const void* x[3]; const float* wa[3][4]; float* out[3][4]; int nt[3]; };
struct Al2Args { const unsigned short* x[3]; const float* wa[3][4]; float* out[3][4]; int nt[3]; };
struct GemmArgs { const void* A[6]; unsigned long long bOff[6]; unsigned long long cOff[6];
                  int M[6]; int nblk[6]; };
struct GatArgs {
    const unsigned short* srcs[3][2]; const int* off[3][2];
    const float* als[3][2]; const float* ald[3][2];
    const unsigned short* hs[3][2];
};
struct P1Args {
    CsrArgs ca;
    const void *W1, *as1, *ad1, *W2, *as2, *ad2, *b1, *b2;
    float *WA1S, *WA1D, *WA2S, *WA2D, *BIAS1, *BIAS2;
    bf16 *W1T, *W2T;
    int *CNT;
    int eTw1, eTw2, eWa1, eWa2, eBias;
    int nbCnt[6];
};
struct P2Args {
    CsrArgs ca;
    const int* OFF; int* POS; unsigned short* SRCS;
    GemmArgs g1;
    Al1Args a1;
    int eFill, eGemm;
    int nbCnt[6];
    int nbAl[3];
};
struct P3Args {
    Al2Args a2;
    GemmArgs g2;
    int eAl2;
    int nbAl[3];
};
struct P2ArgsFix { P2Args p; const bf16* W1T; bf16* HS1; };
struct P3ArgsFix { P3Args p; const bf16* W2T; bf16* HS2; };

// ---------- dtype detection ----------
__global__ void detect_dtype(const unsigned short* __restrict__ u, int* __restrict__ flag){
    int bad = 0;
    for (int i = threadIdx.x; i < 4096; i += 256){
        int e = (u[i] >> 7) & 0xFF;
        if (e >= 0x90) bad = 1;
    }
    if (bad) atomicOr(flag, 1);
}

// ---------- device bodies ----------
static __device__ __forceinline__ void tw_body(const void* W, int f32, bf16* WT,
                                               int Kd, int Nd, int nrel, int blk){
    long long idx = (long long)blk * 256 + threadIdx.x;
    long long tot = (long long)nrel * Kd * Nd;
    if (idx >= tot) return;
    int per = Kd * Nd;
    int r = (int)(idx / per);
    int rem = (int)(idx % per);
    int n = rem / Kd, k = rem % Kd;
    float v = ldx(W, (size_t)r*per + (size_t)k*Nd + n, f32);
    WT[idx] = __float2bfloat16(v);
}

static __device__ __forceinline__ void wa1_body(const void* W1, const void* as1, const void* ad1,
                                                int f32, float* wa_s, float* wa_d, int blk){
    int r = blk >> 1;
    int t = (blk & 1)*256 + threadIdx.x;
    int f = t >> 2, h = t & 3;
    size_t wb = (size_t)r*128*256 + (size_t)f*256 + h*64;
    size_t ab = (size_t)r*256 + h*64;
    float ss = 0.f, sd = 0.f;
    for (int c = 0; c < 64; c++){
        float w = ldx(W1, wb + c, f32);
        ss += w * ldx(as1, ab + c, f32);
        sd += w * ldx(ad1, ab + c, f32);
    }
    wa_s[r*512 + t] = ss; wa_d[r*512 + t] = sd;
}

static __device__ __forceinline__ void wa2_body(const void* W2, const void* as2, const void* ad2,
                                                int f32, float* wa_s, float* wa_d, int r){
    int f = threadIdx.x;
    size_t wb = (size_t)r*256*64 + (size_t)f*64;
    float ss = 0.f, sd = 0.f;
    for (int c = 0; c < 64; c++){
        float w = ldx(W2, wb + c, f32);
        ss += w * ldx(as2, (size_t)r*64 + c, f32);
        sd += w * ldx(ad2, (size_t)r*64 + c, f32);
    }
    wa_s[r*256 + f] = ss; wa_d[r*256 + f] = sd;
}

static __device__ __forceinline__ void bias_body(const void* b1, const void* b2, int f32,
                                                 float* BIAS1, float* BIAS2, int t){
    const int relA[3] = {3, 0, 1};
    const int relB[3] = {5, 4, 2};
    int c = threadIdx.x;
    BIAS1[t*256 + c] = 0.5f*(ldx(b1, relA[t]*256 + c, f32) + ldx(b1, relB[t]*256 + c, f32));
    if (c < 64)
        BIAS2[t*64 + c] = 0.5f*(ldx(b2, relA[t]*64 + c, f32) + ldx(b2, relB[t]*64 + c, f32));
}

static __device__ void al1_body(const Al1Args& a, int f32, int t, int blk, float (*swa)[512]){
    int N = a.nt[t];
    for (int i = threadIdx.x; i < 2048; i += 256) swa[i >> 9][i & 511] = a.wa[t][i >> 9][i & 511];
    __syncthreads();
    int n = blk * 256 + threadIdx.x;
    if (n >= N) return;
    float s[4][4] = {};
    if (f32){
        const float* xr = (const float*)a.x[t] + (size_t)n*128;
        for (int f = 0; f < 128; f++){
            float v = xr[f];
            #pragma unroll
            for (int j = 0; j < 4; j++){
                s[j][0] += v*swa[j][f*4+0]; s[j][1] += v*swa[j][f*4+1];
                s[j][2] += v*swa[j][f*4+2]; s[j][3] += v*swa[j][f*4+3];
            }
        }
    } else {
        const unsigned short* xr = (const unsigned short*)a.x[t] + (size_t)n*128;
        for (int f0 = 0; f0 < 128; f0 += 8){
            us8v v8 = *(const us8v*)(xr + f0);
            #pragma unroll
            for (int jj = 0; jj < 8; jj++){
                float v = us2f(v8[jj]); int f = f0 + jj;
                #pragma unroll
                for (int j = 0; j < 4; j++){
                    s[j][0] += v*swa[j][f*4+0]; s[j][1] += v*swa[j][f*4+1];
                    s[j][2] += v*swa[j][f*4+2]; s[j][3] += v*swa[j][f*4+3];
                }
            }
        }
    }
    #pragma unroll
    for (int j = 0; j < 4; j++)
        *(float4*)(a.out[t][j] + (size_t)n*4) = make_float4(s[j][0], s[j][1], s[j][2], s[j][3]);
}

static __device__ void al2_body(const Al2Args& a, int t, int blk, float (*swa)[256]){
    int N = a.nt[t];
    for (int i = threadIdx.x; i < 1024; i += 256) swa[i >> 8][i & 255] = a.wa[t][i >> 8][i & 255];
    __syncthreads();
    int n = blk * 256 + threadIdx.x;
    if (n >= N) return;
    const unsigned short* xr = a.x[t] + (size_t)n*256;
    float s0 = 0.f, s1 = 0.f, s2 = 0.f, s3 = 0.f;
    for (int f0 = 0; f0 < 256; f0 += 8){
        us8v v8 = *(const us8v*)(xr + f0);
        #pragma unroll
        for (int jj = 0; jj < 8; jj++){
            float v = us2f(v8[jj]); int f = f0 + jj;
            s0 += v*swa[0][f]; s1 += v*swa[1][f]; s2 += v*swa[2][f]; s3 += v*swa[3][f];
        }
    }
    a.out[t][0][n] = s0; a.out[t][1][n] = s1; a.out[t][2][n] = s2; a.out[t][3][n] = s3;
}

static __device__ void gemm_body(const GemmArgs& ga, int af32, const bf16* WT,
                                 bf16* Cb, int N, int K, int nIdx, int yTot,
                                 unsigned short (*As)[40], unsigned short (*Bs)[40]){
    int y = yTot, r = 0;
    while (r < 5 && y >= ga.nblk[r]){ y -= ga.nblk[r]; r++; }
    int M = ga.M[r];
    int m0 = y * 64, n0 = nIdx * 64;
    const void* A = ga.A[r];
    const unsigned short* WTu = (const unsigned short*)WT + ga.bOff[r];
    bf16* C = Cb + ga.cOff[r];
    int tid = threadIdx.x;
    int w = tid >> 6, lane = tid & 63;
    int quad = lane >> 4, l16 = lane & 15;
    int srow = tid >> 2, skc = (tid & 3) * 8;
    f32x4 acc[4] = {};
    for (int k0 = 0; k0 < K; k0 += 32){
        {
            int gr = m0 + srow;
            us8v av;
            if (gr < M){
                if (af32){
                    const float* ap = (const float*)A + (size_t)gr*K + k0 + skc;
                    #pragma unroll
                    for (int j = 0; j < 8; j++) av[j] = f2bu(ap[j]);
                } else {
                    av = *(const us8v*)((const unsigned short*)A + (size_t)gr*K + k0 + skc);
                }
            } else {
                #pragma unroll
                for (int j = 0; j < 8; j++) av[j] = 0;
            }
            *(us8v*)&As[srow][skc] = av;
        }
        *(us8v*)&Bs[srow][skc] = *(const us8v*)(WTu + (size_t)(n0 + srow)*K + k0 + skc);
        __syncthreads();
        short8 af = *(const short8*)&As[w*16 + l16][quad*8];
        #pragma unroll
        for (int c = 0; c < 4; c++){
            short8 bfv = *(const short8*)&Bs[c*16 + l16][quad*8];
            acc[c] = __builtin_amdgcn_mfma_f32_16x16x32_bf16(af, bfv, acc[c], 0, 0, 0);
        }
        __syncthreads();
    }
    #pragma unroll
    for (int c = 0; c < 4; c++){
        #pragma unroll
        for (int i = 0; i < 4; i++){
            int m = m0 + w*16 + quad*4 + i;
            if (m < M) C[(size_t)m*N + n0 + c*16 + l16] = __float2bfloat16(acc[c][i]);
        }
    }
}

// ---------- P1 ----------
__global__ void p1_k(P1Args p, const int* __restrict__ flag){
    int bid = blockIdx.x;
    int f32 = *flag;
    if (bid < p.eTw1){
        tw_body(p.W1, f32, p.W1T, 128, 256, 6, bid);
    } else if (bid < p.eTw2){
        tw_body(p.W2, f32, p.W2T, 256, 64, 6, bid - p.eTw1);
    } else if (bid < p.eWa1){
        wa1_body(p.W1, p.as1, p.ad1, f32, p.WA1S, p.WA1D, bid - p.eTw2);
    } else if (bid < p.eWa2){
        wa2_body(p.W2, p.as2, p.ad2, f32, p.WA2S, p.WA2D, bid - p.eWa1);
    } else if (bid < p.eBias){
        bias_body(p.b1, p.b2, f32, p.BIAS1, p.BIAS2, bid - p.eWa2);
    } else {
        int b = bid - p.eBias, r = 0;
        while (r < 5 && b >= p.nbCnt[r]){ b -= p.nbCnt[r]; r++; }
        int e = b*256 + threadIdx.x;
        if (e < p.ca.ecnt[r]) atomicAdd(&p.CNT[r*OFFSTR + p.ca.dst[r][e]], 1);
    }
}

// ---------- scan ----------
__global__ void csr_scan_all(CsrArgs a, const int* __restrict__ cnt, int* __restrict__ off){
    int r = blockIdx.x;
    int N = a.nd[r];
    const int* c = cnt + r*OFFSTR;
    int* o = off + r*OFFSTR;
    __shared__ int wsum[16];
    __shared__ int base;
    int tid = threadIdx.x, lane = tid & 63, wv = tid >> 6;
    if (tid == 0) base = 0;
    __syncthreads();
    for (int c0 = 0; c0 < N; c0 += 1024){
        int i = c0 + tid;
        int x = (i < N) ? c[i] : 0;
        #pragma unroll
        for (int d = 1; d < 64; d <<= 1){
            int y = __shfl_up(x, d, 64);
            if (lane >= d) x += y;
        }
        if (lane == 63) wsum[wv] = x;
        __syncthreads();
        if (tid == 0){
            int s = 0;
            #pragma unroll
            for (int k = 0; k < 16; k++){ s += wsum[k]; wsum[k] = s; }
        }
        __syncthreads();
        int woff = (wv == 0) ? 0 : wsum[wv - 1];
        if (i < N) o[i + 1] = base + woff + x;
        int total = wsum[15];
        __syncthreads();
        if (tid == 0) base += total;
        __syncthreads();
    }
    if (tid == 0) o[0] = 0;
}

// ---------- P2 ----------
__global__ void p2_kf(P2ArgsFix q, const int* __restrict__ flag){
    __shared__ __align__(16) char smem[10240];
    P2Args& p = q.p;
    int bid = blockIdx.x;
    if (bid < p.eFill){
        int b = bid, r = 0;
        while (r < 5 && b >= p.nbCnt[r]){ b -= p.nbCnt[r]; r++; }
        int e = b*256 + threadIdx.x;
        if (e < p.ca.ecnt[r]){
            int d = p.ca.dst[r][e];
            int pos = atomicAdd(&p.POS[r*OFFSTR + d], 1);
            p.SRCS[p.ca.eoff[r] + p.OFF[r*OFFSTR + d] + pos] = (unsigned short)p.ca.src[r][e];
        }
    } else if (bid < p.eGemm){
        int id = bid - p.eFill;
        int nIdx = id & 3, yTot = id >> 2;
        unsigned short (*As)[40] = (unsigned short(*)[40])smem;
        unsigned short (*Bs)[40] = (unsigned short(*)[40])(smem + 5120);
        gemm_body(p.g1, *flag, q.W1T, q.HS1, 256, 128, nIdx, yTot, As, Bs);
    } else {
        int b = bid - p.eGemm, t = 0;
        while (t < 2 && b >= p.nbAl[t]){ b -= p.nbAl[t]; t++; }
        al1_body(p.a1, *flag, t, b, (float(*)[512])smem);
    }
}

// ---------- P3 ----------
__global__ void p3_kf(P3ArgsFix q){
    __shared__ __align__(16) char smem[10240];
    P3Args& p = q.p;
    int bid = blockIdx.x;
    if (bid < p.eAl2){
        int b = bid, t = 0;
        while (t < 2 && b >= p.nbAl[t]){ b -= p.nbAl[t]; t++; }
        al2_body(p.a2, t, b, (float(*)[256])smem);
    } else {
        int yTot = bid - p.eAl2;
        unsigned short (*As)[40] = (unsigned short(*)[40])smem;
        unsigned short (*Bs)[40] = (unsigned short(*)[40])(smem + 5120);
        gemm_body(p.g2, 0, q.W2T, q.HS2, 64, 256, 0, yTot, As, Bs);
    }
}

// ---------- layer-1 gather: one-pass den folding, 4 edges in flight ----------
__global__ __launch_bounds__(256, 8)
void gat_l1(GatArgs g, const float* __restrict__ BIAS1,
            unsigned short* __restrict__ X2B){
    int gw = blockIdx.x * 4 + (threadIdx.x >> 6);
    if (gw >= NTOT) return;
    int t, w;
    if (gw < NCIRC){ t = 0; w = gw; }
    else if (gw < NCIRC + NMI){ t = 1; w = gw - NCIRC; }
    else { t = 2; w = gw - NCIRC - NMI; }
    int lane = threadIdx.x & 63;
    int hw = lane >> 5, l32 = lane & 31;
    int h = l32 >> 3;
    float fT[8] = {0.f,0.f,0.f,0.f,0.f,0.f,0.f,0.f};
    #pragma unroll
    for (int a = 0; a < 2; a++){
        const float* als = g.als[t][a];
        const unsigned short* srcs = g.srcs[t][a];
        const unsigned short* Hu = g.hs[t][a];
        float aldv = g.ald[t][a][(size_t)w*4 + h];
        int beg = g.off[t][a][w], end = g.off[t][a][w+1];
        float fa[8] = {0.f,0.f,0.f,0.f,0.f,0.f,0.f,0.f};
        float den = 0.f;
        int i = beg + hw;
        for (; i + 6 < end; i += 8){
            int s0 = srcs[i], s1 = srcs[i+2], s2 = srcs[i+4], s3 = srcs[i+6];
            us8v v0 = *(const us8v*)(Hu + (size_t)s0*256 + l32*8);
            us8v v1 = *(const us8v*)(Hu + (size_t)s1*256 + l32*8);
            us8v v2 = *(const us8v*)(Hu + (size_t)s2*256 + l32*8);
            us8v v3 = *(const us8v*)(Hu + (size_t)s3*256 + l32*8);
            float x0 = als[(size_t)s0*4 + h] + aldv;
            float x1 = als[(size_t)s1*4 + h] + aldv;
            float x2 = als[(size_t)s2*4 + h] + aldv;
            float x3 = als[(size_t)s3*4 + h] + aldv;
            float e0 = __expf(x0 > 0.f ? x0 : 0.2f*x0);
            float e1 = __expf(x1 > 0.f ? x1 : 0.2f*x1);
            float e2 = __expf(x2 > 0.f ? x2 : 0.2f*x2);
            float e3 = __expf(x3 > 0.f ? x3 : 0.2f*x3);
            den += e0 + e1 + e2 + e3;
            #pragma unroll
            for (int k = 0; k < 8; k++)
                fa[k] += e0*us2f(v0[k]) + e1*us2f(v1[k]) + e2*us2f(v2[k]) + e3*us2f(v3[k]);
        }
        for (; i < end; i += 2){
            int s = srcs[i];
            us8v v = *(const us8v*)(Hu + (size_t)s*256 + l32*8);
            float xv = als[(size_t)s*4 + h] + aldv;
            float e = __expf(xv > 0.f ? xv : 0.2f*xv);
            den += e;
            #pragma unroll
            for (int k = 0; k < 8; k++) fa[k] += e*us2f(v[k]);
        }
        den += __shfl_xor(den, 32, 64);
        float inv = 1.0f / (den + 1e-16f);
        #pragma unroll
        for (int k = 0; k < 8; k++) fT[k] += fa[k]*inv;
    }
    #pragma unroll
    for (int k = 0; k < 8; k++) fT[k] += __shfl_xor(fT[k], 32, 64);
    if (hw == 0){
        const float* bp = BIAS1 + t*256 + l32*8;
        us8v st;
        #pragma unroll
        for (int k = 0; k < 8; k++){
            float v = fT[k]*0.5f + bp[k];
            v = v > 0.f ? v : (__expf(v) - 1.f);
            st[k] = f2bu(v);
        }
        *(us8v*)(X2B + (size_t)gw*256 + l32*8) = st;
    }
}

// ---------- layer-2 gather: one-pass, quarter-wave, 4 edges staged, fused finalize ----------
__global__ __launch_bounds__(256, 8)
void gat_l2(GatArgs g, const float* __restrict__ BIAS2,
            void* __restrict__ out, const int* __restrict__ flag){
    int gw = blockIdx.x * 4 + (threadIdx.x >> 6);
    if (gw >= NTOT) return;
    int t, w;
    if (gw < NCIRC){ t = 0; w = gw; }
    else if (gw < NCIRC + NMI){ t = 1; w = gw - NCIRC; }
    else { t = 2; w = gw - NCIRC - NMI; }
    int lane = threadIdx.x & 63;
    int qw = lane >> 4, l16 = lane & 15;
    float fT[4] = {0.f,0.f,0.f,0.f};
    #pragma unroll
    for (int a = 0; a < 2; a++){
        const float* als = g.als[t][a];
        const unsigned short* srcs = g.srcs[t][a];
        const unsigned short* Hu = g.hs[t][a];
        float aldv = g.ald[t][a][w];
        int beg = g.off[t][a][w], end = g.off[t][a][w+1];
        float fa[4] = {0.f,0.f,0.f,0.f};
        float den = 0.f;
        int i = beg + qw;
        for (; i + 12 < end; i += 16){
            int s0 = srcs[i], s1 = srcs[i+4], s2 = srcs[i+8], s3 = srcs[i+12];
            ushort4 v0 = *(const ushort4*)(Hu + (size_t)s0*64 + l16*4);
            ushort4 v1 = *(const ushort4*)(Hu + (size_t)s1*64 + l16*4);
            ushort4 v2 = *(const ushort4*)(Hu + (size_t)s2*64 + l16*4);
            ushort4 v3 = *(const ushort4*)(Hu + (size_t)s3*64 + l16*4);
            float x0 = als[s0] + aldv, x1 = als[s1] + aldv;
            float x2 = als[s2] + aldv, x3 = als[s3] + aldv;
            float e0 = __expf(x0 > 0.f ? x0 : 0.2f*x0);
            float e1 = __expf(x1 > 0.f ? x1 : 0.2f*x1);
            float e2 = __expf(x2 > 0.f ? x2 : 0.2f*x2);
            float e3 = __expf(x3 > 0.f ? x3 : 0.2f*x3);
            den += e0 + e1 + e2 + e3;
            fa[0] += e0*us2f(v0.x) + e1*us2f(v1.x) + e2*us2f(v2.x) + e3*us2f(v3.x);
            fa[1] += e0*us2f(v0.y) + e1*us2f(v1.y) + e2*us2f(v2.y) + e3*us2f(v3.y);
            fa[2] += e0*us2f(v0.z) + e1*us2f(v1.z) + e2*us2f(v2.z) + e3*us2f(v3.z);
            fa[3] += e0*us2f(v0.w) + e1*us2f(v1.w) + e2*us2f(v2.w) + e3*us2f(v3.w);
        }
        for (; i < end; i += 4){
            int s = srcs[i];
            ushort4 v = *(const ushort4*)(Hu + (size_t)s*64 + l16*4);
            float xv = als[s] + aldv;
            float e = __expf(xv > 0.f ? xv : 0.2f*xv);
            den += e;
            fa[0] += e*us2f(v.x); fa[1] += e*us2f(v.y);
            fa[2] += e*us2f(v.z); fa[3] += e*us2f(v.w);
        }
        den += __shfl_xor(den, 32, 64);
        den += __shfl_xor(den, 16, 64);
        float inv = 1.0f / (den + 1e-16f);
        #pragma unroll
        for (int k = 0; k < 4; k++) fT[k] += fa[k]*inv;
    }
    #pragma unroll
    for (int k = 0; k < 4; k++){
        fT[k] += __shfl_xor(fT[k], 32, 64);
        fT[k] += __shfl_xor(fT[k], 16, 64);
    }
    const float* bp = BIAS2 + t*64 + l16*4;
    float v0 = fT[0]*0.5f + bp[0];
    float v1 = fT[1]*0.5f + bp[1];
    float v2 = fT[2]*0.5f + bp[2];
    float v3 = fT[3]*0.5f + bp[3];
    float ss = v0*v0 + v1*v1 + v2*v2 + v3*v3;
    #pragma unroll
    for (int mk = 8; mk > 0; mk >>= 1) ss += __shfl_xor(ss, mk, 64);
    float nrm = sqrtf(ss);
    nrm = nrm > 1e-12f ? nrm : 1e-12f;
    float inv_n = 1.0f / nrm;
    if (qw == 0){
        size_t base = (size_t)gw*64 + l16*4;
        if (*flag){
            *(float4*)((float*)out + base) = make_float4(v0*inv_n, v1*inv_n, v2*inv_n, v3*inv_n);
        } else {
            ushort4 st;
            st.x = f2bu(v0*inv_n); st.y = f2bu(v1*inv_n);
            st.z = f2bu(v2*inv_n); st.w = f2bu(v3*inv_n);
            *(ushort4*)((unsigned short*)out + base) = st;
        }
    }
}

// ---------- host ----------
extern "C" void kernel_launch(void* const* d_in, const int* in_sizes, int n_in,
                              void* d_out, int out_size, void* d_ws, size_t ws_size,
                              hipStream_t stream){
    const void* x[3] = {d_in[0], d_in[1], d_in[2]};
    const int Nt[3] = {NCIRC, NMI, NDIS};
    const int* ep[6]; int Ecnt[6];
    for (int r = 0; r < 6; r++){ ep[r] = (const int*)d_in[3 + r]; Ecnt[r] = in_sizes[3 + r] / 2; }
    const void* W1  = d_in[9];
    const void* as1 = d_in[10];
    const void* ad1 = d_in[11];
    const void* b1  = d_in[12];
    const void* W2  = d_in[13];
    const void* as2 = d_in[14];
    const void* ad2 = d_in[15];
    const void* b2  = d_in[16];

    const int rs[6] = {0, 1, 0, 1, 2, 2};
    const int rd[6] = {1, 2, 2, 0, 1, 0};
    const int srel[3][2] = {{0, 2}, {1, 3}, {4, 5}};
    const int drel[3][2] = {{3, 5}, {0, 4}, {1, 2}};
    const int accRow[3] = {0, NCIRC, NCIRC + NMI};

    // ---- workspace layout ----
    float* ws    = (float*)d_ws;
    int*   FLAG  = (int*)ws;
    float* WA1S  = ws + 16;
    float* WA1D  = WA1S + 6*512;
    float* WA2S  = WA1D + 6*512;
    float* WA2D  = WA2S + 6*256;
    float* BIAS1 = WA2D + 6*256;
    float* BIAS2 = BIAS1 + 768;
    float* ALB   = BIAS2 + 192;
    unsigned short* HS1u = (unsigned short*)(ALB + 1008000);
    unsigned short* HS2u = HS1u + 32256000;
    unsigned short* X2Bu = HS2u + 8064000;
    bf16*  W1T   = (bf16*)(X2Bu + 16128000);
    bf16*  W2T   = W1T + 6*256*128;
    int*   CNT   = (int*)(W2T + 6*64*256);
    int*   POS   = CNT + 6*OFFSTR;
    int*   OFF   = POS + 6*OFFSTR;
    unsigned short* SRCS = (unsigned short*)(OFF + 6*OFFSTR);

    int eOff[6]; int acc_e = 0;
    for (int r = 0; r < 6; r++){ eOff[r] = acc_e; acc_e += Ecnt[r]; }
    unsigned long long hs1off[6], hs2off[6];
    { unsigned long long o1 = 0, o2 = 0;
      for (int r = 0; r < 6; r++){ hs1off[r] = o1; o1 += (unsigned long long)Nt[rs[r]]*256;
                                   hs2off[r] = o2; o2 += (unsigned long long)Nt[rs[r]]*64; } }
    float *AL1S[6], *AL1D[6], *AL2S[6], *AL2D[6];
    { size_t o = 0;
      for (int r = 0; r < 6; r++){ AL1S[r] = ALB + o; o += (size_t)Nt[rs[r]]*4; }
      for (int r = 0; r < 6; r++){ AL1D[r] = ALB + o; o += (size_t)Nt[rd[r]]*4; }
      size_t o2 = 0;
      for (int r = 0; r < 6; r++){ AL2S[r] = ALB + o2; o2 += (size_t)Nt[rs[r]]; }
      for (int r = 0; r < 6; r++){ AL2D[r] = ALB + o2; o2 += (size_t)Nt[rd[r]]; } }

    CsrArgs ca;
    for (int r = 0; r < 6; r++){
        ca.src[r] = ep[r]; ca.dst[r] = ep[r] + Ecnt[r];
        ca.ecnt[r] = Ecnt[r]; ca.eoff[r] = eOff[r]; ca.nd[r] = Nt[rd[r]];
    }

    hipMemsetAsync(FLAG, 0, sizeof(int), stream);
    hipMemsetAsync(CNT, 0, (size_t)12*OFFSTR*sizeof(int), stream);
    detect_dtype<<<1, 256, 0, stream>>>((const unsigned short*)d_in[0], FLAG);

    // ---- P1 ----
    P1Args p1;
    p1.ca = ca;
    p1.W1 = W1; p1.as1 = as1; p1.ad1 = ad1; p1.W2 = W2; p1.as2 = as2; p1.ad2 = ad2;
    p1.b1 = b1; p1.b2 = b2;
    p1.WA1S = WA1S; p1.WA1D = WA1D; p1.WA2S = WA2S; p1.WA2D = WA2D;
    p1.BIAS1 = BIAS1; p1.BIAS2 = BIAS2;
    p1.W1T = W1T; p1.W2T = W2T; p1.CNT = CNT;
    int nTw1 = cdiv(6LL*128*256, 256), nTw2 = cdiv(6LL*256*64, 256);
    p1.eTw1 = nTw1; p1.eTw2 = nTw1 + nTw2;
    p1.eWa1 = p1.eTw2 + 12; p1.eWa2 = p1.eWa1 + 6; p1.eBias = p1.eWa2 + 3;
    int cntBlk = 0;
    for (int r = 0; r < 6; r++){ p1.nbCnt[r] = cdiv(Ecnt[r], 256); cntBlk += p1.nbCnt[r]; }
    p1_k<<<p1.eBias + cntBlk, 256, 0, stream>>>(p1, FLAG);

    // ---- scan ----
    csr_scan_all<<<6, 1024, 0, stream>>>(ca, CNT, OFF);

    // ---- P2 ----
    P2ArgsFix q2;
    q2.p.ca = ca; q2.p.OFF = OFF; q2.p.POS = POS; q2.p.SRCS = SRCS;
    int totBlk1 = 0;
    for (int r = 0; r < 6; r++){
        q2.p.g1.A[r] = x[rs[r]]; q2.p.g1.bOff[r] = (unsigned long long)r*256*128;
        q2.p.g1.cOff[r] = hs1off[r]; q2.p.g1.M[r] = Nt[rs[r]];
        q2.p.g1.nblk[r] = cdiv(Nt[rs[r]], 64); totBlk1 += q2.p.g1.nblk[r];
        q2.p.nbCnt[r] = p1.nbCnt[r];
    }
    for (int t = 0; t < 3; t++){
        q2.p.a1.x[t] = x[t]; q2.p.a1.nt[t] = Nt[t];
        q2.p.nbAl[t] = cdiv(Nt[t], 256);
        for (int j = 0; j < 2; j++){
            q2.p.a1.wa[t][j]   = WA1S + srel[t][j]*512;  q2.p.a1.out[t][j]   = AL1S[srel[t][j]];
            q2.p.a1.wa[t][j+2] = WA1D + drel[t][j]*512;  q2.p.a1.out[t][j+2] = AL1D[drel[t][j]];
        }
    }
    q2.p.eFill = cntBlk; q2.p.eGemm = cntBlk + 4*totBlk1;
    q2.W1T = W1T; q2.HS1 = (bf16*)HS1u;
    int nAl1 = q2.p.nbAl[0] + q2.p.nbAl[1] + q2.p.nbAl[2];
    p2_kf<<<q2.p.eGemm + nAl1, 256, 0, stream>>>(q2, FLAG);

    // ---- gat_l1 ----
    GatArgs gl1;
    for (int t = 0; t < 3; t++)
        for (int a = 0; a < 2; a++){
            int r = drel[t][a];
            gl1.srcs[t][a] = SRCS + eOff[r]; gl1.off[t][a] = OFF + r*OFFSTR;
            gl1.als[t][a] = AL1S[r]; gl1.ald[t][a] = AL1D[r];
            gl1.hs[t][a] = HS1u + hs1off[r];
        }
    gat_l1<<<cdiv(NTOT, 4), 256, 0, stream>>>(gl1, BIAS1, X2Bu);

    // ---- P3 ----
    P3ArgsFix q3;
    int totBlk2 = 0;
    for (int r = 0; r < 6; r++){
        q3.p.g2.A[r] = X2Bu + (size_t)accRow[rs[r]]*256;
        q3.p.g2.bOff[r] = (unsigned long long)r*64*256;
        q3.p.g2.cOff[r] = hs2off[r]; q3.p.g2.M[r] = Nt[rs[r]];
        q3.p.g2.nblk[r] = cdiv(Nt[rs[r]], 64); totBlk2 += q3.p.g2.nblk[r];
    }
    for (int t = 0; t < 3; t++){
        q3.p.a2.x[t] = X2Bu + (size_t)accRow[t]*256; q3.p.a2.nt[t] = Nt[t];
        q3.p.nbAl[t] = cdiv(Nt[t], 256);
        for (int j = 0; j < 2; j++){
            q3.p.a2.wa[t][j]   = WA2S + srel[t][j]*256;  q3.p.a2.out[t][j]   = AL2S[srel[t][j]];
            q3.p.a2.wa[t][j+2] = WA2D + drel[t][j]*256;  q3.p.a2.out[t][j+2] = AL2D[drel[t][j]];
        }
    }
    q3.p.eAl2 = q3.p.nbAl[0] + q3.p.nbAl[1] + q3.p.nbAl[2];
    q3.W2T = W2T; q3.HS2 = (bf16*)HS2u;
    p3_kf<<<q3.p.eAl2 + totBlk2, 256, 0, stream>>>(q3);

    // ---- gat_l2 ----
    GatArgs gl2;
    for (int t = 0; t < 3; t++)
        for (int a = 0; a < 2; a++){
            int r = drel[t][a];
            gl2.srcs[t][a] = SRCS + eOff[r]; gl2.off[t][a] = OFF + r*OFFSTR;
            gl2.als[t][a] = AL2S[r]; gl2.ald[t][a] = AL2D[r];
            gl2.hs[t][a] = HS2u + hs2off[r];
        }
    gat_l2<<<cdiv(NTOT, 4), 256, 0, stream>>>(gl2, BIAS2, d_out, FLAG);
}

// Round 10
// 634.208 us; speedup vs baseline: 1.2048x; 1.2048x over previous
//
#include <hip/hip_runtime.h>
#include <hip/hip_bf16.h>
#include <math.h>

#define NCIRC 40000
#define NMI   15000
#define NDIS  8000
#define NTOT  (NCIRC + NMI + NDIS)
#define OFFSTR 40064

typedef __hip_bfloat16 bf16;
typedef __attribute__((ext_vector_type(8))) short short8;
typedef __attribute__((ext_vector_type(4))) float f32x4;
typedef __attribute__((ext_vector_type(8))) unsigned short us8v;

static __device__ __forceinline__ float us2f(unsigned short u){ return __uint_as_float(((unsigned)u) << 16); }
static __device__ __forceinline__ unsigned short f2bu(float v){
    bf16 t = __float2bfloat16(v);
    return *reinterpret_cast<unsigned short*>(&t);
}
static __device__ __forceinline__ float ldx(const void* p, size_t i, int f32){
    return f32 ? ((const float*)p)[i] : __bfloat162float(((const bf16*)p)[i]);
}
static inline unsigned cdiv(long long a, long long b){ return (unsigned)((a + b - 1) / b); }

// ---------- arg structs ----------
struct CsrArgs {
    const int* src[6]; const int* dst[6];
    int ecnt[6]; int eoff[6]; int nd[6];
};
struct Al1Args { const void* x[3]; const float* wa[3][4]; float* out[3][4]; int nt[3]; };
struct Al2Args { const unsigned short* x[3]; const float* wa[3][4]; float* out[3][4]; int nt[3]; };
struct GemmArgs { const void* A[6]; unsigned long long bOff[6]; unsigned long long cOff[6];
                  int M[6]; int nblk[6]; };
struct GatArgs {
    const unsigned short* srcs[3][2]; const int* off[3][2];
    const float* als[3][2]; const float* ald[3][2];
    const unsigned short* hs[3][2];
};
struct P1Args {
    CsrArgs ca;
    const void *W1, *as1, *ad1, *W2, *as2, *ad2, *b1, *b2;
    float *WA1S, *WA1D, *WA2S, *WA2D, *BIAS1, *BIAS2;
    bf16 *W1T, *W2T;
    int *CNT;
    int eTw1, eTw2, eWa1, eWa2, eBias;
    int nbCnt[6];
};
struct P2Args {
    CsrArgs ca;
    const int* OFF; int* POS; unsigned short* SRCS;
    GemmArgs g1;
    Al1Args a1;
    int eFill, eGemm;
    int nbCnt[6];
    int nbAl[3];
};
struct P3Args {
    Al2Args a2;
    GemmArgs g2;
    int eAl2;
    int nbAl[3];
};
struct P2ArgsFix { P2Args p; const bf16* W1T; bf16* HS1; };
struct P3ArgsFix { P3Args p; const bf16* W2T; bf16* HS2; };

// ---------- dtype detection ----------
__global__ void detect_dtype(const unsigned short* __restrict__ u, int* __restrict__ flag){
    int bad = 0;
    for (int i = threadIdx.x; i < 4096; i += 256){
        int e = (u[i] >> 7) & 0xFF;
        if (e >= 0x90) bad = 1;
    }
    if (bad) atomicOr(flag, 1);
}

// ---------- device bodies ----------
static __device__ __forceinline__ void tw_body(const void* W, int f32, bf16* WT,
                                               int Kd, int Nd, int nrel, int blk){
    long long idx = (long long)blk * 256 + threadIdx.x;
    long long tot = (long long)nrel * Kd * Nd;
    if (idx >= tot) return;
    int per = Kd * Nd;
    int r = (int)(idx / per);
    int rem = (int)(idx % per);
    int n = rem / Kd, k = rem % Kd;
    float v = ldx(W, (size_t)r*per + (size_t)k*Nd + n, f32);
    WT[idx] = __float2bfloat16(v);
}

static __device__ __forceinline__ void wa1_body(const void* W1, const void* as1, const void* ad1,
                                                int f32, float* wa_s, float* wa_d, int blk){
    int r = blk >> 1;
    int t = (blk & 1)*256 + threadIdx.x;
    int f = t >> 2, h = t & 3;
    size_t wb = (size_t)r*128*256 + (size_t)f*256 + h*64;
    size_t ab = (size_t)r*256 + h*64;
    float ss = 0.f, sd = 0.f;
    for (int c = 0; c < 64; c++){
        float w = ldx(W1, wb + c, f32);
        ss += w * ldx(as1, ab + c, f32);
        sd += w * ldx(ad1, ab + c, f32);
    }
    wa_s[r*512 + t] = ss; wa_d[r*512 + t] = sd;
}

static __device__ __forceinline__ void wa2_body(const void* W2, const void* as2, const void* ad2,
                                                int f32, float* wa_s, float* wa_d, int r){
    int f = threadIdx.x;
    size_t wb = (size_t)r*256*64 + (size_t)f*64;
    float ss = 0.f, sd = 0.f;
    for (int c = 0; c < 64; c++){
        float w = ldx(W2, wb + c, f32);
        ss += w * ldx(as2, (size_t)r*64 + c, f32);
        sd += w * ldx(ad2, (size_t)r*64 + c, f32);
    }
    wa_s[r*256 + f] = ss; wa_d[r*256 + f] = sd;
}

static __device__ __forceinline__ void bias_body(const void* b1, const void* b2, int f32,
                                                 float* BIAS1, float* BIAS2, int t){
    const int relA[3] = {3, 0, 1};
    const int relB[3] = {5, 4, 2};
    int c = threadIdx.x;
    BIAS1[t*256 + c] = 0.5f*(ldx(b1, relA[t]*256 + c, f32) + ldx(b1, relB[t]*256 + c, f32));
    if (c < 64)
        BIAS2[t*64 + c] = 0.5f*(ldx(b2, relA[t]*64 + c, f32) + ldx(b2, relB[t]*64 + c, f32));
}

static __device__ void al1_body(const Al1Args& a, int f32, int t, int blk, float (*swa)[512]){
    int N = a.nt[t];
    for (int i = threadIdx.x; i < 2048; i += 256) swa[i >> 9][i & 511] = a.wa[t][i >> 9][i & 511];
    __syncthreads();
    int n = blk * 256 + threadIdx.x;
    if (n >= N) return;
    float s[4][4] = {};
    if (f32){
        const float* xr = (const float*)a.x[t] + (size_t)n*128;
        for (int f = 0; f < 128; f++){
            float v = xr[f];
            #pragma unroll
            for (int j = 0; j < 4; j++){
                s[j][0] += v*swa[j][f*4+0]; s[j][1] += v*swa[j][f*4+1];
                s[j][2] += v*swa[j][f*4+2]; s[j][3] += v*swa[j][f*4+3];
            }
        }
    } else {
        const unsigned short* xr = (const unsigned short*)a.x[t] + (size_t)n*128;
        for (int f0 = 0; f0 < 128; f0 += 8){
            us8v v8 = *(const us8v*)(xr + f0);
            #pragma unroll
            for (int jj = 0; jj < 8; jj++){
                float v = us2f(v8[jj]); int f = f0 + jj;
                #pragma unroll
                for (int j = 0; j < 4; j++){
                    s[j][0] += v*swa[j][f*4+0]; s[j][1] += v*swa[j][f*4+1];
                    s[j][2] += v*swa[j][f*4+2]; s[j][3] += v*swa[j][f*4+3];
                }
            }
        }
    }
    #pragma unroll
    for (int j = 0; j < 4; j++)
        *(float4*)(a.out[t][j] + (size_t)n*4) = make_float4(s[j][0], s[j][1], s[j][2], s[j][3]);
}

static __device__ void al2_body(const Al2Args& a, int t, int blk, float (*swa)[256]){
    int N = a.nt[t];
    for (int i = threadIdx.x; i < 1024; i += 256) swa[i >> 8][i & 255] = a.wa[t][i >> 8][i & 255];
    __syncthreads();
    int n = blk * 256 + threadIdx.x;
    if (n >= N) return;
    const unsigned short* xr = a.x[t] + (size_t)n*256;
    float s0 = 0.f, s1 = 0.f, s2 = 0.f, s3 = 0.f;
    for (int f0 = 0; f0 < 256; f0 += 8){
        us8v v8 = *(const us8v*)(xr + f0);
        #pragma unroll
        for (int jj = 0; jj < 8; jj++){
            float v = us2f(v8[jj]); int f = f0 + jj;
            s0 += v*swa[0][f]; s1 += v*swa[1][f]; s2 += v*swa[2][f]; s3 += v*swa[3][f];
        }
    }
    a.out[t][0][n] = s0; a.out[t][1][n] = s1; a.out[t][2][n] = s2; a.out[t][3][n] = s3;
}

static __device__ void gemm_body(const GemmArgs& ga, int af32, const bf16* WT,
                                 bf16* Cb, int N, int K, int nIdx, int yTot,
                                 unsigned short (*As)[40], unsigned short (*Bs)[40]){
    int y = yTot, r = 0;
    while (r < 5 && y >= ga.nblk[r]){ y -= ga.nblk[r]; r++; }
    int M = ga.M[r];
    int m0 = y * 64, n0 = nIdx * 64;
    const void* A = ga.A[r];
    const unsigned short* WTu = (const unsigned short*)WT + ga.bOff[r];
    bf16* C = Cb + ga.cOff[r];
    int tid = threadIdx.x;
    int w = tid >> 6, lane = tid & 63;
    int quad = lane >> 4, l16 = lane & 15;
    int srow = tid >> 2, skc = (tid & 3) * 8;
    f32x4 acc[4] = {};
    for (int k0 = 0; k0 < K; k0 += 32){
        {
            int gr = m0 + srow;
            us8v av;
            if (gr < M){
                if (af32){
                    const float* ap = (const float*)A + (size_t)gr*K + k0 + skc;
                    #pragma unroll
                    for (int j = 0; j < 8; j++) av[j] = f2bu(ap[j]);
                } else {
                    av = *(const us8v*)((const unsigned short*)A + (size_t)gr*K + k0 + skc);
                }
            } else {
                #pragma unroll
                for (int j = 0; j < 8; j++) av[j] = 0;
            }
            *(us8v*)&As[srow][skc] = av;
        }
        *(us8v*)&Bs[srow][skc] = *(const us8v*)(WTu + (size_t)(n0 + srow)*K + k0 + skc);
        __syncthreads();
        short8 af = *(const short8*)&As[w*16 + l16][quad*8];
        #pragma unroll
        for (int c = 0; c < 4; c++){
            short8 bfv = *(const short8*)&Bs[c*16 + l16][quad*8];
            acc[c] = __builtin_amdgcn_mfma_f32_16x16x32_bf16(af, bfv, acc[c], 0, 0, 0);
        }
        __syncthreads();
    }
    #pragma unroll
    for (int c = 0; c < 4; c++){
        #pragma unroll
        for (int i = 0; i < 4; i++){
            int m = m0 + w*16 + quad*4 + i;
            if (m < M) C[(size_t)m*N + n0 + c*16 + l16] = __float2bfloat16(acc[c][i]);
        }
    }
}

// ---------- P1 ----------
__global__ void p1_k(P1Args p, const int* __restrict__ flag){
    int bid = blockIdx.x;
    int f32 = *flag;
    if (bid < p.eTw1){
        tw_body(p.W1, f32, p.W1T, 128, 256, 6, bid);
    } else if (bid < p.eTw2){
        tw_body(p.W2, f32, p.W2T, 256, 64, 6, bid - p.eTw1);
    } else if (bid < p.eWa1){
        wa1_body(p.W1, p.as1, p.ad1, f32, p.WA1S, p.WA1D, bid - p.eTw2);
    } else if (bid < p.eWa2){
        wa2_body(p.W2, p.as2, p.ad2, f32, p.WA2S, p.WA2D, bid - p.eWa1);
    } else if (bid < p.eBias){
        bias_body(p.b1, p.b2, f32, p.BIAS1, p.BIAS2, bid - p.eWa2);
    } else {
        int b = bid - p.eBias, r = 0;
        while (r < 5 && b >= p.nbCnt[r]){ b -= p.nbCnt[r]; r++; }
        int e = b*256 + threadIdx.x;
        if (e < p.ca.ecnt[r]) atomicAdd(&p.CNT[r*OFFSTR + p.ca.dst[r][e]], 1);
    }
}

// ---------- scan ----------
__global__ void csr_scan_all(CsrArgs a, const int* __restrict__ cnt, int* __restrict__ off){
    int r = blockIdx.x;
    int N = a.nd[r];
    const int* c = cnt + r*OFFSTR;
    int* o = off + r*OFFSTR;
    __shared__ int wsum[16];
    __shared__ int base;
    int tid = threadIdx.x, lane = tid & 63, wv = tid >> 6;
    if (tid == 0) base = 0;
    __syncthreads();
    for (int c0 = 0; c0 < N; c0 += 1024){
        int i = c0 + tid;
        int x = (i < N) ? c[i] : 0;
        #pragma unroll
        for (int d = 1; d < 64; d <<= 1){
            int y = __shfl_up(x, d, 64);
            if (lane >= d) x += y;
        }
        if (lane == 63) wsum[wv] = x;
        __syncthreads();
        if (tid == 0){
            int s = 0;
            #pragma unroll
            for (int k = 0; k < 16; k++){ s += wsum[k]; wsum[k] = s; }
        }
        __syncthreads();
        int woff = (wv == 0) ? 0 : wsum[wv - 1];
        if (i < N) o[i + 1] = base + woff + x;
        int total = wsum[15];
        __syncthreads();
        if (tid == 0) base += total;
        __syncthreads();
    }
    if (tid == 0) o[0] = 0;
}

// ---------- P2 ----------
__global__ void p2_kf(P2ArgsFix q, const int* __restrict__ flag){
    __shared__ __align__(16) char smem[10240];
    P2Args& p = q.p;
    int bid = blockIdx.x;
    if (bid < p.eFill){
        int b = bid, r = 0;
        while (r < 5 && b >= p.nbCnt[r]){ b -= p.nbCnt[r]; r++; }
        int e = b*256 + threadIdx.x;
        if (e < p.ca.ecnt[r]){
            int d = p.ca.dst[r][e];
            int pos = atomicAdd(&p.POS[r*OFFSTR + d], 1);
            p.SRCS[p.ca.eoff[r] + p.OFF[r*OFFSTR + d] + pos] = (unsigned short)p.ca.src[r][e];
        }
    } else if (bid < p.eGemm){
        int id = bid - p.eFill;
        int nIdx = id & 3, yTot = id >> 2;
        unsigned short (*As)[40] = (unsigned short(*)[40])smem;
        unsigned short (*Bs)[40] = (unsigned short(*)[40])(smem + 5120);
        gemm_body(p.g1, *flag, q.W1T, q.HS1, 256, 128, nIdx, yTot, As, Bs);
    } else {
        int b = bid - p.eGemm, t = 0;
        while (t < 2 && b >= p.nbAl[t]){ b -= p.nbAl[t]; t++; }
        al1_body(p.a1, *flag, t, b, (float(*)[512])smem);
    }
}

// ---------- P3 ----------
__global__ void p3_kf(P3ArgsFix q){
    __shared__ __align__(16) char smem[10240];
    P3Args& p = q.p;
    int bid = blockIdx.x;
    if (bid < p.eAl2){
        int b = bid, t = 0;
        while (t < 2 && b >= p.nbAl[t]){ b -= p.nbAl[t]; t++; }
        al2_body(p.a2, t, b, (float(*)[256])smem);
    } else {
        int yTot = bid - p.eAl2;
        unsigned short (*As)[40] = (unsigned short(*)[40])smem;
        unsigned short (*Bs)[40] = (unsigned short(*)[40])(smem + 5120);
        gemm_body(p.g2, 0, q.W2T, q.HS2, 64, 256, 0, yTot, As, Bs);
    }
}

// ---------- layer-1 gather: one-pass den folding, 4 edges in flight, no launch bounds ----------
__global__ void gat_l1(GatArgs g, const float* __restrict__ BIAS1,
                       unsigned short* __restrict__ X2B){
    int gw = blockIdx.x * 4 + (threadIdx.x >> 6);
    if (gw >= NTOT) return;
    int t, w;
    if (gw < NCIRC){ t = 0; w = gw; }
    else if (gw < NCIRC + NMI){ t = 1; w = gw - NCIRC; }
    else { t = 2; w = gw - NCIRC - NMI; }
    int lane = threadIdx.x & 63;
    int hw = lane >> 5, l32 = lane & 31;
    int h = l32 >> 3;
    float fT[8] = {0.f,0.f,0.f,0.f,0.f,0.f,0.f,0.f};
    #pragma unroll
    for (int a = 0; a < 2; a++){
        const float* als = g.als[t][a];
        const unsigned short* srcs = g.srcs[t][a];
        const unsigned short* Hu = g.hs[t][a];
        float aldv = g.ald[t][a][(size_t)w*4 + h];
        int beg = g.off[t][a][w], end = g.off[t][a][w+1];
        float fa[8] = {0.f,0.f,0.f,0.f,0.f,0.f,0.f,0.f};
        float den = 0.f;
        int i = beg + hw;
        for (; i + 6 < end; i += 8){
            int s0 = srcs[i], s1 = srcs[i+2], s2 = srcs[i+4], s3 = srcs[i+6];
            us8v v0 = *(const us8v*)(Hu + (size_t)s0*256 + l32*8);
            us8v v1 = *(const us8v*)(Hu + (size_t)s1*256 + l32*8);
            us8v v2 = *(const us8v*)(Hu + (size_t)s2*256 + l32*8);
            us8v v3 = *(const us8v*)(Hu + (size_t)s3*256 + l32*8);
            float x0 = als[(size_t)s0*4 + h] + aldv;
            float x1 = als[(size_t)s1*4 + h] + aldv;
            float x2 = als[(size_t)s2*4 + h] + aldv;
            float x3 = als[(size_t)s3*4 + h] + aldv;
            float e0 = __expf(x0 > 0.f ? x0 : 0.2f*x0);
            float e1 = __expf(x1 > 0.f ? x1 : 0.2f*x1);
            float e2 = __expf(x2 > 0.f ? x2 : 0.2f*x2);
            float e3 = __expf(x3 > 0.f ? x3 : 0.2f*x3);
            den += e0 + e1 + e2 + e3;
            #pragma unroll
            for (int k = 0; k < 8; k++)
                fa[k] += e0*us2f(v0[k]) + e1*us2f(v1[k]) + e2*us2f(v2[k]) + e3*us2f(v3[k]);
        }
        for (; i < end; i += 2){
            int s = srcs[i];
            us8v v = *(const us8v*)(Hu + (size_t)s*256 + l32*8);
            float xv = als[(size_t)s*4 + h] + aldv;
            float e = __expf(xv > 0.f ? xv : 0.2f*xv);
            den += e;
            #pragma unroll
            for (int k = 0; k < 8; k++) fa[k] += e*us2f(v[k]);
        }
        den += __shfl_xor(den, 32, 64);
        float inv = 1.0f / (den + 1e-16f);
        #pragma unroll
        for (int k = 0; k < 8; k++) fT[k] += fa[k]*inv;
    }
    #pragma unroll
    for (int k = 0; k < 8; k++) fT[k] += __shfl_xor(fT[k], 32, 64);
    if (hw == 0){
        const float* bp = BIAS1 + t*256 + l32*8;
        us8v st;
        #pragma unroll
        for (int k = 0; k < 8; k++){
            float v = fT[k]*0.5f + bp[k];
            v = v > 0.f ? v : (__expf(v) - 1.f);
            st[k] = f2bu(v);
        }
        *(us8v*)(X2B + (size_t)gw*256 + l32*8) = st;
    }
}

// ---------- layer-2 gather: one-pass, quarter-wave, 4 edges staged, fused finalize ----------
__global__ void gat_l2(GatArgs g, const float* __restrict__ BIAS2,
                       void* __restrict__ out, const int* __restrict__ flag){
    int gw = blockIdx.x * 4 + (threadIdx.x >> 6);
    if (gw >= NTOT) return;
    int t, w;
    if (gw < NCIRC){ t = 0; w = gw; }
    else if (gw < NCIRC + NMI){ t = 1; w = gw - NCIRC; }
    else { t = 2; w = gw - NCIRC - NMI; }
    int lane = threadIdx.x & 63;
    int qw = lane >> 4, l16 = lane & 15;
    float fT[4] = {0.f,0.f,0.f,0.f};
    #pragma unroll
    for (int a = 0; a < 2; a++){
        const float* als = g.als[t][a];
        const unsigned short* srcs = g.srcs[t][a];
        const unsigned short* Hu = g.hs[t][a];
        float aldv = g.ald[t][a][w];
        int beg = g.off[t][a][w], end = g.off[t][a][w+1];
        float fa[4] = {0.f,0.f,0.f,0.f};
        float den = 0.f;
        int i = beg + qw;
        for (; i + 12 < end; i += 16){
            int s0 = srcs[i], s1 = srcs[i+4], s2 = srcs[i+8], s3 = srcs[i+12];
            ushort4 v0 = *(const ushort4*)(Hu + (size_t)s0*64 + l16*4);
            ushort4 v1 = *(const ushort4*)(Hu + (size_t)s1*64 + l16*4);
            ushort4 v2 = *(const ushort4*)(Hu + (size_t)s2*64 + l16*4);
            ushort4 v3 = *(const ushort4*)(Hu + (size_t)s3*64 + l16*4);
            float x0 = als[s0] + aldv, x1 = als[s1] + aldv;
            float x2 = als[s2] + aldv, x3 = als[s3] + aldv;
            float e0 = __expf(x0 > 0.f ? x0 : 0.2f*x0);
            float e1 = __expf(x1 > 0.f ? x1 : 0.2f*x1);
            float e2 = __expf(x2 > 0.f ? x2 : 0.2f*x2);
            float e3 = __expf(x3 > 0.f ? x3 : 0.2f*x3);
            den += e0 + e1 + e2 + e3;
            fa[0] += e0*us2f(v0.x) + e1*us2f(v1.x) + e2*us2f(v2.x) + e3*us2f(v3.x);
            fa[1] += e0*us2f(v0.y) + e1*us2f(v1.y) + e2*us2f(v2.y) + e3*us2f(v3.y);
            fa[2] += e0*us2f(v0.z) + e1*us2f(v1.z) + e2*us2f(v2.z) + e3*us2f(v3.z);
            fa[3] += e0*us2f(v0.w) + e1*us2f(v1.w) + e2*us2f(v2.w) + e3*us2f(v3.w);
        }
        for (; i < end; i += 4){
            int s = srcs[i];
            ushort4 v = *(const ushort4*)(Hu + (size_t)s*64 + l16*4);
            float xv = als[s] + aldv;
            float e = __expf(xv > 0.f ? xv : 0.2f*xv);
            den += e;
            fa[0] += e*us2f(v.x); fa[1] += e*us2f(v.y);
            fa[2] += e*us2f(v.z); fa[3] += e*us2f(v.w);
        }
        den += __shfl_xor(den, 32, 64);
        den += __shfl_xor(den, 16, 64);
        float inv = 1.0f / (den + 1e-16f);
        #pragma unroll
        for (int k = 0; k < 4; k++) fT[k] += fa[k]*inv;
    }
    #pragma unroll
    for (int k = 0; k < 4; k++){
        fT[k] += __shfl_xor(fT[k], 32, 64);
        fT[k] += __shfl_xor(fT[k], 16, 64);
    }
    const float* bp = BIAS2 + t*64 + l16*4;
    float v0 = fT[0]*0.5f + bp[0];
    float v1 = fT[1]*0.5f + bp[1];
    float v2 = fT[2]*0.5f + bp[2];
    float v3 = fT[3]*0.5f + bp[3];
    float ss = v0*v0 + v1*v1 + v2*v2 + v3*v3;
    #pragma unroll
    for (int mk = 8; mk > 0; mk >>= 1) ss += __shfl_xor(ss, mk, 64);
    float nrm = sqrtf(ss);
    nrm = nrm > 1e-12f ? nrm : 1e-12f;
    float inv_n = 1.0f / nrm;
    if (qw == 0){
        size_t base = (size_t)gw*64 + l16*4;
        if (*flag){
            *(float4*)((float*)out + base) = make_float4(v0*inv_n, v1*inv_n, v2*inv_n, v3*inv_n);
        } else {
            ushort4 st;
            st.x = f2bu(v0*inv_n); st.y = f2bu(v1*inv_n);
            st.z = f2bu(v2*inv_n); st.w = f2bu(v3*inv_n);
            *(ushort4*)((unsigned short*)out + base) = st;
        }
    }
}

// ---------- host ----------
extern "C" void kernel_launch(void* const* d_in, const int* in_sizes, int n_in,
                              void* d_out, int out_size, void* d_ws, size_t ws_size,
                              hipStream_t stream){
    const void* x[3] = {d_in[0], d_in[1], d_in[2]};
    const int Nt[3] = {NCIRC, NMI, NDIS};
    const int* ep[6]; int Ecnt[6];
    for (int r = 0; r < 6; r++){ ep[r] = (const int*)d_in[3 + r]; Ecnt[r] = in_sizes[3 + r] / 2; }
    const void* W1  = d_in[9];
    const void* as1 = d_in[10];
    const void* ad1 = d_in[11];
    const void* b1  = d_in[12];
    const void* W2  = d_in[13];
    const void* as2 = d_in[14];
    const void* ad2 = d_in[15];
    const void* b2  = d_in[16];

    const int rs[6] = {0, 1, 0, 1, 2, 2};
    const int rd[6] = {1, 2, 2, 0, 1, 0};
    const int srel[3][2] = {{0, 2}, {1, 3}, {4, 5}};
    const int drel[3][2] = {{3, 5}, {0, 4}, {1, 2}};
    const int accRow[3] = {0, NCIRC, NCIRC + NMI};

    // ---- workspace layout ----
    float* ws    = (float*)d_ws;
    int*   FLAG  = (int*)ws;
    float* WA1S  = ws + 16;
    float* WA1D  = WA1S + 6*512;
    float* WA2S  = WA1D + 6*512;
    float* WA2D  = WA2S + 6*256;
    float* BIAS1 = WA2D + 6*256;
    float* BIAS2 = BIAS1 + 768;
    float* ALB   = BIAS2 + 192;
    unsigned short* HS1u = (unsigned short*)(ALB + 1008000);
    unsigned short* HS2u = HS1u + 32256000;
    unsigned short* X2Bu = HS2u + 8064000;
    bf16*  W1T   = (bf16*)(X2Bu + 16128000);
    bf16*  W2T   = W1T + 6*256*128;
    int*   CNT   = (int*)(W2T + 6*64*256);
    int*   POS   = CNT + 6*OFFSTR;
    int*   OFF   = POS + 6*OFFSTR;
    unsigned short* SRCS = (unsigned short*)(OFF + 6*OFFSTR);

    int eOff[6]; int acc_e = 0;
    for (int r = 0; r < 6; r++){ eOff[r] = acc_e; acc_e += Ecnt[r]; }
    unsigned long long hs1off[6], hs2off[6];
    { unsigned long long o1 = 0, o2 = 0;
      for (int r = 0; r < 6; r++){ hs1off[r] = o1; o1 += (unsigned long long)Nt[rs[r]]*256;
                                   hs2off[r] = o2; o2 += (unsigned long long)Nt[rs[r]]*64; } }
    float *AL1S[6], *AL1D[6], *AL2S[6], *AL2D[6];
    { size_t o = 0;
      for (int r = 0; r < 6; r++){ AL1S[r] = ALB + o; o += (size_t)Nt[rs[r]]*4; }
      for (int r = 0; r < 6; r++){ AL1D[r] = ALB + o; o += (size_t)Nt[rd[r]]*4; }
      size_t o2 = 0;
      for (int r = 0; r < 6; r++){ AL2S[r] = ALB + o2; o2 += (size_t)Nt[rs[r]]; }
      for (int r = 0; r < 6; r++){ AL2D[r] = ALB + o2; o2 += (size_t)Nt[rd[r]]; } }

    CsrArgs ca;
    for (int r = 0; r < 6; r++){
        ca.src[r] = ep[r]; ca.dst[r] = ep[r] + Ecnt[r];
        ca.ecnt[r] = Ecnt[r]; ca.eoff[r] = eOff[r]; ca.nd[r] = Nt[rd[r]];
    }

    hipMemsetAsync(FLAG, 0, sizeof(int), stream);
    hipMemsetAsync(CNT, 0, (size_t)12*OFFSTR*sizeof(int), stream);
    detect_dtype<<<1, 256, 0, stream>>>((const unsigned short*)d_in[0], FLAG);

    // ---- P1 ----
    P1Args p1;
    p1.ca = ca;
    p1.W1 = W1; p1.as1 = as1; p1.ad1 = ad1; p1.W2 = W2; p1.as2 = as2; p1.ad2 = ad2;
    p1.b1 = b1; p1.b2 = b2;
    p1.WA1S = WA1S; p1.WA1D = WA1D; p1.WA2S = WA2S; p1.WA2D = WA2D;
    p1.BIAS1 = BIAS1; p1.BIAS2 = BIAS2;
    p1.W1T = W1T; p1.W2T = W2T; p1.CNT = CNT;
    int nTw1 = cdiv(6LL*128*256, 256), nTw2 = cdiv(6LL*256*64, 256);
    p1.eTw1 = nTw1; p1.eTw2 = nTw1 + nTw2;
    p1.eWa1 = p1.eTw2 + 12; p1.eWa2 = p1.eWa1 + 6; p1.eBias = p1.eWa2 + 3;
    int cntBlk = 0;
    for (int r = 0; r < 6; r++){ p1.nbCnt[r] = cdiv(Ecnt[r], 256); cntBlk += p1.nbCnt[r]; }
    p1_k<<<p1.eBias + cntBlk, 256, 0, stream>>>(p1, FLAG);

    // ---- scan ----
    csr_scan_all<<<6, 1024, 0, stream>>>(ca, CNT, OFF);

    // ---- P2 ----
    P2ArgsFix q2;
    q2.p.ca = ca; q2.p.OFF = OFF; q2.p.POS = POS; q2.p.SRCS = SRCS;
    int totBlk1 = 0;
    for (int r = 0; r < 6; r++){
        q2.p.g1.A[r] = x[rs[r]]; q2.p.g1.bOff[r] = (unsigned long long)r*256*128;
        q2.p.g1.cOff[r] = hs1off[r]; q2.p.g1.M[r] = Nt[rs[r]];
        q2.p.g1.nblk[r] = cdiv(Nt[rs[r]], 64); totBlk1 += q2.p.g1.nblk[r];
        q2.p.nbCnt[r] = p1.nbCnt[r];
    }
    for (int t = 0; t < 3; t++){
        q2.p.a1.x[t] = x[t]; q2.p.a1.nt[t] = Nt[t];
        q2.p.nbAl[t] = cdiv(Nt[t], 256);
        for (int j = 0; j < 2; j++){
            q2.p.a1.wa[t][j]   = WA1S + srel[t][j]*512;  q2.p.a1.out[t][j]   = AL1S[srel[t][j]];
            q2.p.a1.wa[t][j+2] = WA1D + drel[t][j]*512;  q2.p.a1.out[t][j+2] = AL1D[drel[t][j]];
        }
    }
    q2.p.eFill = cntBlk; q2.p.eGemm = cntBlk + 4*totBlk1;
    q2.W1T = W1T; q2.HS1 = (bf16*)HS1u;
    int nAl1 = q2.p.nbAl[0] + q2.p.nbAl[1] + q2.p.nbAl[2];
    p2_kf<<<q2.p.eGemm + nAl1, 256, 0, stream>>>(q2, FLAG);

    // ---- gat_l1 ----
    GatArgs gl1;
    for (int t = 0; t < 3; t++)
        for (int a = 0; a < 2; a++){
            int r = drel[t][a];
            gl1.srcs[t][a] = SRCS + eOff[r]; gl1.off[t][a] = OFF + r*OFFSTR;
            gl1.als[t][a] = AL1S[r]; gl1.ald[t][a] = AL1D[r];
            gl1.hs[t][a] = HS1u + hs1off[r];
        }
    gat_l1<<<cdiv(NTOT, 4), 256, 0, stream>>>(gl1, BIAS1, X2Bu);

    // ---- P3 ----
    P3ArgsFix q3;
    int totBlk2 = 0;
    for (int r = 0; r < 6; r++){
        q3.p.g2.A[r] = X2Bu + (size_t)accRow[rs[r]]*256;
        q3.p.g2.bOff[r] = (unsigned long long)r*64*256;
        q3.p.g2.cOff[r] = hs2off[r]; q3.p.g2.M[r] = Nt[rs[r]];
        q3.p.g2.nblk[r] = cdiv(Nt[rs[r]], 64); totBlk2 += q3.p.g2.nblk[r];
    }
    for (int t = 0; t < 3; t++){
        q3.p.a2.x[t] = X2Bu + (size_t)accRow[t]*256; q3.p.a2.nt[t] = Nt[t];
        q3.p.nbAl[t] = cdiv(Nt[t], 256);
        for (int j = 0; j < 2; j++){
            q3.p.a2.wa[t][j]   = WA2S + srel[t][j]*256;  q3.p.a2.out[t][j]   = AL2S[srel[t][j]];
            q3.p.a2.wa[t][j+2] = WA2D + drel[t][j]*256;  q3.p.a2.out[t][j+2] = AL2D[drel[t][j]];
        }
    }
    q3.p.eAl2 = q3.p.nbAl[0] + q3.p.nbAl[1] + q3.p.nbAl[2];
    q3.W2T = W2T; q3.HS2 = (bf16*)HS2u;
    p3_kf<<<q3.p.eAl2 + totBlk2, 256, 0, stream>>>(q3);

    // ---- gat_l2 ----
    GatArgs gl2;
    for (int t = 0; t < 3; t++)
        for (int a = 0; a < 2; a++){
            int r = drel[t][a];
            gl2.srcs[t][a] = SRCS + eOff[r]; gl2.off[t][a] = OFF + r*OFFSTR;
            gl2.als[t][a] = AL2S[r]; gl2.ald[t][a] = AL2D[r];
            gl2.hs[t][a] = HS2u + hs2off[r];
        }
    gat_l2<<<cdiv(NTOT, 4), 256, 0, stream>>>(gl2, BIAS2, d_out, FLAG);
}

// Round 11
// 607.439 us; speedup vs baseline: 1.2579x; 1.0441x over previous
//
#include <hip/hip_runtime.h>
#include <hip/hip_bf16.h>
#include <math.h>

#define NCIRC 40000
#define NMI   15000
#define NDIS  8000
#define NTOT  (NCIRC + NMI + NDIS)
#define OFFSTR 40064

typedef __hip_bfloat16 bf16;
typedef __attribute__((ext_vector_type(8))) short short8;
typedef __attribute__((ext_vector_type(4))) float f32x4;
typedef __attribute__((ext_vector_type(8))) unsigned short us8v;

static __device__ __forceinline__ float us2f(unsigned short u){ return __uint_as_float(((unsigned)u) << 16); }
static __device__ __forceinline__ unsigned short f2bu(float v){
    bf16 t = __float2bfloat16(v);
    return *reinterpret_cast<unsigned short*>(&t);
}
static __device__ __forceinline__ float ldx(const void* p, size_t i, int f32){
    return f32 ? ((const float*)p)[i] : __bfloat162float(((const bf16*)p)[i]);
}
static inline unsigned cdiv(long long a, long long b){ return (unsigned)((a + b - 1) / b); }

// ---------- arg structs ----------
struct CsrArgs {
    const int* src[6]; const int* dst[6];
    int ecnt[6]; int eoff[6]; int nd[6];
};
struct ScanArgs { int start[6]; int nch[6]; int nd[6]; };
struct Al1Args { const void* x[3]; const float* wa[3][4]; float* out[3][4]; int nt[3]; };
struct Al2Args { const unsigned short* x[3]; const float* wa[3][4]; float* out[3][4]; int nt[3]; };
struct GemmArgs { const void* A[6]; unsigned long long bOff[6]; unsigned long long cOff[6];
                  int M[6]; int nblk[6]; };
struct GatArgs {
    const unsigned short* srcs[3][2]; const int* off[3][2];
    const float* als[3][2]; const float* ald[3][2];
    const unsigned short* hs[3][2];
};
struct P1Args {
    CsrArgs ca;
    const void *W1, *as1, *ad1, *W2, *as2, *ad2, *b1, *b2;
    float *WA1S, *WA1D, *WA2S, *WA2D, *BIAS1, *BIAS2;
    bf16 *W1T, *W2T;
    int *CNT;
    int eTw1, eTw2, eWa1, eWa2, eBias;
    int nbCnt[6];
};
struct P2Args {
    CsrArgs ca;
    const int* OFF; int* POS; unsigned short* SRCS;
    GemmArgs g1;
    Al1Args a1;
    int eFill, eGemm;
    int nbCnt[6];
    int nbAl[3];
};
struct P3Args {
    Al2Args a2;
    GemmArgs g2;
    int eAl2;
    int nbAl[3];
};
struct P2ArgsFix { P2Args p; const bf16* W1T; bf16* HS1; };
struct P3ArgsFix { P3Args p; const bf16* W2T; bf16* HS2; };

// ---------- init: block 0 = dtype detect (writes FLAG directly), blocks 1..63 zero CNT+POS ----------
__global__ void init_k(const unsigned short* __restrict__ u, int* __restrict__ flag,
                       int* __restrict__ zbase, int zcount){
    if (blockIdx.x == 0){
        __shared__ int sbad;
        if (threadIdx.x == 0) sbad = 0;
        __syncthreads();
        int bad = 0;
        for (int i = threadIdx.x; i < 4096; i += 256){
            int e = (u[i] >> 7) & 0xFF;
            if (e >= 0x90) bad = 1;
        }
        if (bad) atomicOr(&sbad, 1);
        __syncthreads();
        if (threadIdx.x == 0) *flag = sbad;
    } else {
        for (int i = (blockIdx.x - 1)*256 + threadIdx.x; i < zcount; i += 63*256)
            zbase[i] = 0;
    }
}

// ---------- device bodies ----------
static __device__ __forceinline__ void tw_body(const void* W, int f32, bf16* WT,
                                               int Kd, int Nd, int nrel, int blk){
    long long idx = (long long)blk * 256 + threadIdx.x;
    long long tot = (long long)nrel * Kd * Nd;
    if (idx >= tot) return;
    int per = Kd * Nd;
    int r = (int)(idx / per);
    int rem = (int)(idx % per);
    int n = rem / Kd, k = rem % Kd;
    float v = ldx(W, (size_t)r*per + (size_t)k*Nd + n, f32);
    WT[idx] = __float2bfloat16(v);
}

static __device__ __forceinline__ void wa1_body(const void* W1, const void* as1, const void* ad1,
                                                int f32, float* wa_s, float* wa_d, int blk){
    int r = blk >> 1;
    int t = (blk & 1)*256 + threadIdx.x;
    int f = t >> 2, h = t & 3;
    size_t wb = (size_t)r*128*256 + (size_t)f*256 + h*64;
    size_t ab = (size_t)r*256 + h*64;
    float ss = 0.f, sd = 0.f;
    for (int c = 0; c < 64; c++){
        float w = ldx(W1, wb + c, f32);
        ss += w * ldx(as1, ab + c, f32);
        sd += w * ldx(ad1, ab + c, f32);
    }
    wa_s[r*512 + t] = ss; wa_d[r*512 + t] = sd;
}

static __device__ __forceinline__ void wa2_body(const void* W2, const void* as2, const void* ad2,
                                                int f32, float* wa_s, float* wa_d, int r){
    int f = threadIdx.x;
    size_t wb = (size_t)r*256*64 + (size_t)f*64;
    float ss = 0.f, sd = 0.f;
    for (int c = 0; c < 64; c++){
        float w = ldx(W2, wb + c, f32);
        ss += w * ldx(as2, (size_t)r*64 + c, f32);
        sd += w * ldx(ad2, (size_t)r*64 + c, f32);
    }
    wa_s[r*256 + f] = ss; wa_d[r*256 + f] = sd;
}

static __device__ __forceinline__ void bias_body(const void* b1, const void* b2, int f32,
                                                 float* BIAS1, float* BIAS2, int t){
    const int relA[3] = {3, 0, 1};
    const int relB[3] = {5, 4, 2};
    int c = threadIdx.x;
    BIAS1[t*256 + c] = 0.5f*(ldx(b1, relA[t]*256 + c, f32) + ldx(b1, relB[t]*256 + c, f32));
    if (c < 64)
        BIAS2[t*64 + c] = 0.5f*(ldx(b2, relA[t]*64 + c, f32) + ldx(b2, relB[t]*64 + c, f32));
}

static __device__ void al1_body(const Al1Args& a, int f32, int t, int blk, float (*swa)[512]){
    int N = a.nt[t];
    for (int i = threadIdx.x; i < 2048; i += 256) swa[i >> 9][i & 511] = a.wa[t][i >> 9][i & 511];
    __syncthreads();
    int n = blk * 256 + threadIdx.x;
    if (n >= N) return;
    float s[4][4] = {};
    if (f32){
        const float* xr = (const float*)a.x[t] + (size_t)n*128;
        for (int f = 0; f < 128; f++){
            float v = xr[f];
            #pragma unroll
            for (int j = 0; j < 4; j++){
                s[j][0] += v*swa[j][f*4+0]; s[j][1] += v*swa[j][f*4+1];
                s[j][2] += v*swa[j][f*4+2]; s[j][3] += v*swa[j][f*4+3];
            }
        }
    } else {
        const unsigned short* xr = (const unsigned short*)a.x[t] + (size_t)n*128;
        for (int f0 = 0; f0 < 128; f0 += 8){
            us8v v8 = *(const us8v*)(xr + f0);
            #pragma unroll
            for (int jj = 0; jj < 8; jj++){
                float v = us2f(v8[jj]); int f = f0 + jj;
                #pragma unroll
                for (int j = 0; j < 4; j++){
                    s[j][0] += v*swa[j][f*4+0]; s[j][1] += v*swa[j][f*4+1];
                    s[j][2] += v*swa[j][f*4+2]; s[j][3] += v*swa[j][f*4+3];
                }
            }
        }
    }
    #pragma unroll
    for (int j = 0; j < 4; j++)
        *(float4*)(a.out[t][j] + (size_t)n*4) = make_float4(s[j][0], s[j][1], s[j][2], s[j][3]);
}

static __device__ void al2_body(const Al2Args& a, int t, int blk, float (*swa)[256]){
    int N = a.nt[t];
    for (int i = threadIdx.x; i < 1024; i += 256) swa[i >> 8][i & 255] = a.wa[t][i >> 8][i & 255];
    __syncthreads();
    int n = blk * 256 + threadIdx.x;
    if (n >= N) return;
    const unsigned short* xr = a.x[t] + (size_t)n*256;
    float s0 = 0.f, s1 = 0.f, s2 = 0.f, s3 = 0.f;
    for (int f0 = 0; f0 < 256; f0 += 8){
        us8v v8 = *(const us8v*)(xr + f0);
        #pragma unroll
        for (int jj = 0; jj < 8; jj++){
            float v = us2f(v8[jj]); int f = f0 + jj;
            s0 += v*swa[0][f]; s1 += v*swa[1][f]; s2 += v*swa[2][f]; s3 += v*swa[3][f];
        }
    }
    a.out[t][0][n] = s0; a.out[t][1][n] = s1; a.out[t][2][n] = s2; a.out[t][3][n] = s3;
}

static __device__ void gemm_body(const GemmArgs& ga, int af32, const bf16* WT,
                                 bf16* Cb, int N, int K, int nIdx, int yTot,
                                 unsigned short (*As)[40], unsigned short (*Bs)[40]){
    int y = yTot, r = 0;
    while (r < 5 && y >= ga.nblk[r]){ y -= ga.nblk[r]; r++; }
    int M = ga.M[r];
    int m0 = y * 64, n0 = nIdx * 64;
    const void* A = ga.A[r];
    const unsigned short* WTu = (const unsigned short*)WT + ga.bOff[r];
    bf16* C = Cb + ga.cOff[r];
    int tid = threadIdx.x;
    int w = tid >> 6, lane = tid & 63;
    int quad = lane >> 4, l16 = lane & 15;
    int srow = tid >> 2, skc = (tid & 3) * 8;
    f32x4 acc[4] = {};
    for (int k0 = 0; k0 < K; k0 += 32){
        {
            int gr = m0 + srow;
            us8v av;
            if (gr < M){
                if (af32){
                    const float* ap = (const float*)A + (size_t)gr*K + k0 + skc;
                    #pragma unroll
                    for (int j = 0; j < 8; j++) av[j] = f2bu(ap[j]);
                } else {
                    av = *(const us8v*)((const unsigned short*)A + (size_t)gr*K + k0 + skc);
                }
            } else {
                #pragma unroll
                for (int j = 0; j < 8; j++) av[j] = 0;
            }
            *(us8v*)&As[srow][skc] = av;
        }
        *(us8v*)&Bs[srow][skc] = *(const us8v*)(WTu + (size_t)(n0 + srow)*K + k0 + skc);
        __syncthreads();
        short8 af = *(const short8*)&As[w*16 + l16][quad*8];
        #pragma unroll
        for (int c = 0; c < 4; c++){
            short8 bfv = *(const short8*)&Bs[c*16 + l16][quad*8];
            acc[c] = __builtin_amdgcn_mfma_f32_16x16x32_bf16(af, bfv, acc[c], 0, 0, 0);
        }
        __syncthreads();
    }
    #pragma unroll
    for (int c = 0; c < 4; c++){
        #pragma unroll
        for (int i = 0; i < 4; i++){
            int m = m0 + w*16 + quad*4 + i;
            if (m < M) C[(size_t)m*N + n0 + c*16 + l16] = __float2bfloat16(acc[c][i]);
        }
    }
}

// ---------- P1 ----------
__global__ void p1_k(P1Args p, const int* __restrict__ flag){
    int bid = blockIdx.x;
    int f32 = *flag;
    if (bid < p.eTw1){
        tw_body(p.W1, f32, p.W1T, 128, 256, 6, bid);
    } else if (bid < p.eTw2){
        tw_body(p.W2, f32, p.W2T, 256, 64, 6, bid - p.eTw1);
    } else if (bid < p.eWa1){
        wa1_body(p.W1, p.as1, p.ad1, f32, p.WA1S, p.WA1D, bid - p.eTw2);
    } else if (bid < p.eWa2){
        wa2_body(p.W2, p.as2, p.ad2, f32, p.WA2S, p.WA2D, bid - p.eWa1);
    } else if (bid < p.eBias){
        bias_body(p.b1, p.b2, f32, p.BIAS1, p.BIAS2, bid - p.eWa2);
    } else {
        int b = bid - p.eBias, r = 0;
        while (r < 5 && b >= p.nbCnt[r]){ b -= p.nbCnt[r]; r++; }
        int e = b*256 + threadIdx.x;
        if (e < p.ca.ecnt[r]) atomicAdd(&p.CNT[r*OFFSTR + p.ca.dst[r][e]], 1);
    }
}

// ---------- parallel 3-phase scan ----------
// phase A: one block per 1024-chunk: local inclusive scan, chunk total -> CHT
__global__ void scan_a(ScanArgs s, const int* __restrict__ cnt, int* __restrict__ off,
                       int* __restrict__ CHT){
    int b = blockIdx.x, r = 0;
    while (r < 5 && b >= s.start[r+1]) r++;
    int chunk = b - s.start[r];
    int N = s.nd[r];
    int tid = threadIdx.x, lane = tid & 63, wv = tid >> 6;
    __shared__ int wsum[16];
    int i = chunk*1024 + tid;
    int x = (i < N) ? cnt[r*OFFSTR + i] : 0;
    #pragma unroll
    for (int d = 1; d < 64; d <<= 1){
        int y = __shfl_up(x, d, 64);
        if (lane >= d) x += y;
    }
    if (lane == 63) wsum[wv] = x;
    __syncthreads();
    if (tid == 0){
        int acc = 0;
        #pragma unroll
        for (int k = 0; k < 16; k++){ acc += wsum[k]; wsum[k] = acc; }
    }
    __syncthreads();
    int incl = x + ((wv == 0) ? 0 : wsum[wv - 1]);
    if (i < N) off[r*OFFSTR + i + 1] = incl;
    if (tid == 1023) CHT[r*64 + chunk] = incl;
}

// phase B: exclusive-scan chunk totals per relation (1 block; 6 lanes work serially)
__global__ void scan_b(ScanArgs s, int* __restrict__ CHT){
    int r = threadIdx.x;
    if (r < 6){
        int acc = 0;
        for (int c = 0; c < s.nch[r]; c++){
            int v = CHT[r*64 + c];
            CHT[r*64 + c] = acc;
            acc += v;
        }
    }
}

// phase C: add chunk bases; zero off[0]
__global__ void scan_c(ScanArgs s, int* __restrict__ off, const int* __restrict__ CHT){
    int b = blockIdx.x, r = 0;
    while (r < 5 && b >= s.start[r+1]) r++;
    int chunk = b - s.start[r];
    int N = s.nd[r];
    int i = chunk*1024 + threadIdx.x;
    int addv = CHT[r*64 + chunk];
    if (i < N) off[r*OFFSTR + i + 1] += addv;
    if (chunk == 0 && threadIdx.x == 0) off[r*OFFSTR] = 0;
}

// ---------- P2 ----------
__global__ void p2_kf(P2ArgsFix q, const int* __restrict__ flag){
    __shared__ __align__(16) char smem[10240];
    P2Args& p = q.p;
    int bid = blockIdx.x;
    if (bid < p.eFill){
        int b = bid, r = 0;
        while (r < 5 && b >= p.nbCnt[r]){ b -= p.nbCnt[r]; r++; }
        int e = b*256 + threadIdx.x;
        if (e < p.ca.ecnt[r]){
            int d = p.ca.dst[r][e];
            int pos = atomicAdd(&p.POS[r*OFFSTR + d], 1);
            p.SRCS[p.ca.eoff[r] + p.OFF[r*OFFSTR + d] + pos] = (unsigned short)p.ca.src[r][e];
        }
    } else if (bid < p.eGemm){
        int id = bid - p.eFill;
        int nIdx = id & 3, yTot = id >> 2;
        unsigned short (*As)[40] = (unsigned short(*)[40])smem;
        unsigned short (*Bs)[40] = (unsigned short(*)[40])(smem + 5120);
        gemm_body(p.g1, *flag, q.W1T, q.HS1, 256, 128, nIdx, yTot, As, Bs);
    } else {
        int b = bid - p.eGemm, t = 0;
        while (t < 2 && b >= p.nbAl[t]){ b -= p.nbAl[t]; t++; }
        al1_body(p.a1, *flag, t, b, (float(*)[512])smem);
    }
}

// ---------- P3 ----------
__global__ void p3_kf(P3ArgsFix q){
    __shared__ __align__(16) char smem[10240];
    P3Args& p = q.p;
    int bid = blockIdx.x;
    if (bid < p.eAl2){
        int b = bid, t = 0;
        while (t < 2 && b >= p.nbAl[t]){ b -= p.nbAl[t]; t++; }
        al2_body(p.a2, t, b, (float(*)[256])smem);
    } else {
        int yTot = bid - p.eAl2;
        unsigned short (*As)[40] = (unsigned short(*)[40])smem;
        unsigned short (*Bs)[40] = (unsigned short(*)[40])(smem + 5120);
        gemm_body(p.g2, 0, q.W2T, q.HS2, 64, 256, 0, yTot, As, Bs);
    }
}

// ---------- layer-1 gather: one-pass den folding, 4 edges in flight ----------
__global__ void gat_l1(GatArgs g, const float* __restrict__ BIAS1,
                       unsigned short* __restrict__ X2B){
    int gw = blockIdx.x * 4 + (threadIdx.x >> 6);
    if (gw >= NTOT) return;
    int t, w;
    if (gw < NCIRC){ t = 0; w = gw; }
    else if (gw < NCIRC + NMI){ t = 1; w = gw - NCIRC; }
    else { t = 2; w = gw - NCIRC - NMI; }
    int lane = threadIdx.x & 63;
    int hw = lane >> 5, l32 = lane & 31;
    int h = l32 >> 3;
    float fT[8] = {0.f,0.f,0.f,0.f,0.f,0.f,0.f,0.f};
    #pragma unroll
    for (int a = 0; a < 2; a++){
        const float* als = g.als[t][a];
        const unsigned short* srcs = g.srcs[t][a];
        const unsigned short* Hu = g.hs[t][a];
        float aldv = g.ald[t][a][(size_t)w*4 + h];
        int beg = g.off[t][a][w], end = g.off[t][a][w+1];
        float fa[8] = {0.f,0.f,0.f,0.f,0.f,0.f,0.f,0.f};
        float den = 0.f;
        int i = beg + hw;
        for (; i + 6 < end; i += 8){
            int s0 = srcs[i], s1 = srcs[i+2], s2 = srcs[i+4], s3 = srcs[i+6];
            us8v v0 = *(const us8v*)(Hu + (size_t)s0*256 + l32*8);
            us8v v1 = *(const us8v*)(Hu + (size_t)s1*256 + l32*8);
            us8v v2 = *(const us8v*)(Hu + (size_t)s2*256 + l32*8);
            us8v v3 = *(const us8v*)(Hu + (size_t)s3*256 + l32*8);
            float x0 = als[(size_t)s0*4 + h] + aldv;
            float x1 = als[(size_t)s1*4 + h] + aldv;
            float x2 = als[(size_t)s2*4 + h] + aldv;
            float x3 = als[(size_t)s3*4 + h] + aldv;
            float e0 = __expf(x0 > 0.f ? x0 : 0.2f*x0);
            float e1 = __expf(x1 > 0.f ? x1 : 0.2f*x1);
            float e2 = __expf(x2 > 0.f ? x2 : 0.2f*x2);
            float e3 = __expf(x3 > 0.f ? x3 : 0.2f*x3);
            den += e0 + e1 + e2 + e3;
            #pragma unroll
            for (int k = 0; k < 8; k++)
                fa[k] += e0*us2f(v0[k]) + e1*us2f(v1[k]) + e2*us2f(v2[k]) + e3*us2f(v3[k]);
        }
        for (; i < end; i += 2){
            int s = srcs[i];
            us8v v = *(const us8v*)(Hu + (size_t)s*256 + l32*8);
            float xv = als[(size_t)s*4 + h] + aldv;
            float e = __expf(xv > 0.f ? xv : 0.2f*xv);
            den += e;
            #pragma unroll
            for (int k = 0; k < 8; k++) fa[k] += e*us2f(v[k]);
        }
        den += __shfl_xor(den, 32, 64);
        float inv = 1.0f / (den + 1e-16f);
        #pragma unroll
        for (int k = 0; k < 8; k++) fT[k] += fa[k]*inv;
    }
    #pragma unroll
    for (int k = 0; k < 8; k++) fT[k] += __shfl_xor(fT[k], 32, 64);
    if (hw == 0){
        const float* bp = BIAS1 + t*256 + l32*8;
        us8v st;
        #pragma unroll
        for (int k = 0; k < 8; k++){
            float v = fT[k]*0.5f + bp[k];
            v = v > 0.f ? v : (__expf(v) - 1.f);
            st[k] = f2bu(v);
        }
        *(us8v*)(X2B + (size_t)gw*256 + l32*8) = st;
    }
}

// ---------- layer-2 gather: one-pass, quarter-wave, 4 edges staged, fused finalize ----------
__global__ void gat_l2(GatArgs g, const float* __restrict__ BIAS2,
                       void* __restrict__ out, const int* __restrict__ flag){
    int gw = blockIdx.x * 4 + (threadIdx.x >> 6);
    if (gw >= NTOT) return;
    int t, w;
    if (gw < NCIRC){ t = 0; w = gw; }
    else if (gw < NCIRC + NMI){ t = 1; w = gw - NCIRC; }
    else { t = 2; w = gw - NCIRC - NMI; }
    int lane = threadIdx.x & 63;
    int qw = lane >> 4, l16 = lane & 15;
    float fT[4] = {0.f,0.f,0.f,0.f};
    #pragma unroll
    for (int a = 0; a < 2; a++){
        const float* als = g.als[t][a];
        const unsigned short* srcs = g.srcs[t][a];
        const unsigned short* Hu = g.hs[t][a];
        float aldv = g.ald[t][a][w];
        int beg = g.off[t][a][w], end = g.off[t][a][w+1];
        float fa[4] = {0.f,0.f,0.f,0.f};
        float den = 0.f;
        int i = beg + qw;
        for (; i + 12 < end; i += 16){
            int s0 = srcs[i], s1 = srcs[i+4], s2 = srcs[i+8], s3 = srcs[i+12];
            ushort4 v0 = *(const ushort4*)(Hu + (size_t)s0*64 + l16*4);
            ushort4 v1 = *(const ushort4*)(Hu + (size_t)s1*64 + l16*4);
            ushort4 v2 = *(const ushort4*)(Hu + (size_t)s2*64 + l16*4);
            ushort4 v3 = *(const ushort4*)(Hu + (size_t)s3*64 + l16*4);
            float x0 = als[s0] + aldv, x1 = als[s1] + aldv;
            float x2 = als[s2] + aldv, x3 = als[s3] + aldv;
            float e0 = __expf(x0 > 0.f ? x0 : 0.2f*x0);
            float e1 = __expf(x1 > 0.f ? x1 : 0.2f*x1);
            float e2 = __expf(x2 > 0.f ? x2 : 0.2f*x2);
            float e3 = __expf(x3 > 0.f ? x3 : 0.2f*x3);
            den += e0 + e1 + e2 + e3;
            fa[0] += e0*us2f(v0.x) + e1*us2f(v1.x) + e2*us2f(v2.x) + e3*us2f(v3.x);
            fa[1] += e0*us2f(v0.y) + e1*us2f(v1.y) + e2*us2f(v2.y) + e3*us2f(v3.y);
            fa[2] += e0*us2f(v0.z) + e1*us2f(v1.z) + e2*us2f(v2.z) + e3*us2f(v3.z);
            fa[3] += e0*us2f(v0.w) + e1*us2f(v1.w) + e2*us2f(v2.w) + e3*us2f(v3.w);
        }
        for (; i < end; i += 4){
            int s = srcs[i];
            ushort4 v = *(const ushort4*)(Hu + (size_t)s*64 + l16*4);
            float xv = als[s] + aldv;
            float e = __expf(xv > 0.f ? xv : 0.2f*xv);
            den += e;
            fa[0] += e*us2f(v.x); fa[1] += e*us2f(v.y);
            fa[2] += e*us2f(v.z); fa[3] += e*us2f(v.w);
        }
        den += __shfl_xor(den, 32, 64);
        den += __shfl_xor(den, 16, 64);
        float inv = 1.0f / (den + 1e-16f);
        #pragma unroll
        for (int k = 0; k < 4; k++) fT[k] += fa[k]*inv;
    }
    #pragma unroll
    for (int k = 0; k < 4; k++){
        fT[k] += __shfl_xor(fT[k], 32, 64);
        fT[k] += __shfl_xor(fT[k], 16, 64);
    }
    const float* bp = BIAS2 + t*64 + l16*4;
    float v0 = fT[0]*0.5f + bp[0];
    float v1 = fT[1]*0.5f + bp[1];
    float v2 = fT[2]*0.5f + bp[2];
    float v3 = fT[3]*0.5f + bp[3];
    float ss = v0*v0 + v1*v1 + v2*v2 + v3*v3;
    #pragma unroll
    for (int mk = 8; mk > 0; mk >>= 1) ss += __shfl_xor(ss, mk, 64);
    float nrm = sqrtf(ss);
    nrm = nrm > 1e-12f ? nrm : 1e-12f;
    float inv_n = 1.0f / nrm;
    if (qw == 0){
        size_t base = (size_t)gw*64 + l16*4;
        if (*flag){
            *(float4*)((float*)out + base) = make_float4(v0*inv_n, v1*inv_n, v2*inv_n, v3*inv_n);
        } else {
            ushort4 st;
            st.x = f2bu(v0*inv_n); st.y = f2bu(v1*inv_n);
            st.z = f2bu(v2*inv_n); st.w = f2bu(v3*inv_n);
            *(ushort4*)((unsigned short*)out + base) = st;
        }
    }
}

// ---------- host ----------
extern "C" void kernel_launch(void* const* d_in, const int* in_sizes, int n_in,
                              void* d_out, int out_size, void* d_ws, size_t ws_size,
                              hipStream_t stream){
    const void* x[3] = {d_in[0], d_in[1], d_in[2]};
    const int Nt[3] = {NCIRC, NMI, NDIS};
    const int* ep[6]; int Ecnt[6];
    for (int r = 0; r < 6; r++){ ep[r] = (const int*)d_in[3 + r]; Ecnt[r] = in_sizes[3 + r] / 2; }
    const void* W1  = d_in[9];
    const void* as1 = d_in[10];
    const void* ad1 = d_in[11];
    const void* b1  = d_in[12];
    const void* W2  = d_in[13];
    const void* as2 = d_in[14];
    const void* ad2 = d_in[15];
    const void* b2  = d_in[16];

    const int rs[6] = {0, 1, 0, 1, 2, 2};
    const int rd[6] = {1, 2, 2, 0, 1, 0};
    const int srel[3][2] = {{0, 2}, {1, 3}, {4, 5}};
    const int drel[3][2] = {{3, 5}, {0, 4}, {1, 2}};
    const int accRow[3] = {0, NCIRC, NCIRC + NMI};

    // ---- workspace layout ----
    float* ws    = (float*)d_ws;
    int*   FLAG  = (int*)ws;
    float* WA1S  = ws + 16;
    float* WA1D  = WA1S + 6*512;
    float* WA2S  = WA1D + 6*512;
    float* WA2D  = WA2S + 6*256;
    float* BIAS1 = WA2D + 6*256;
    float* BIAS2 = BIAS1 + 768;
    float* ALB   = BIAS2 + 192;
    unsigned short* HS1u = (unsigned short*)(ALB + 1008000);
    unsigned short* HS2u = HS1u + 32256000;
    unsigned short* X2Bu = HS2u + 8064000;
    bf16*  W1T   = (bf16*)(X2Bu + 16128000);
    bf16*  W2T   = W1T + 6*256*128;
    int*   CNT   = (int*)(W2T + 6*64*256);
    int*   POS   = CNT + 6*OFFSTR;
    int*   OFF   = POS + 6*OFFSTR;
    int*   CHT   = OFF + 6*OFFSTR;                      // 6*64 chunk totals
    unsigned short* SRCS = (unsigned short*)(CHT + 6*64);

    int eOff[6]; int acc_e = 0;
    for (int r = 0; r < 6; r++){ eOff[r] = acc_e; acc_e += Ecnt[r]; }
    unsigned long long hs1off[6], hs2off[6];
    { unsigned long long o1 = 0, o2 = 0;
      for (int r = 0; r < 6; r++){ hs1off[r] = o1; o1 += (unsigned long long)Nt[rs[r]]*256;
                                   hs2off[r] = o2; o2 += (unsigned long long)Nt[rs[r]]*64; } }
    float *AL1S[6], *AL1D[6], *AL2S[6], *AL2D[6];
    { size_t o = 0;
      for (int r = 0; r < 6; r++){ AL1S[r] = ALB + o; o += (size_t)Nt[rs[r]]*4; }
      for (int r = 0; r < 6; r++){ AL1D[r] = ALB + o; o += (size_t)Nt[rd[r]]*4; }
      size_t o2 = 0;
      for (int r = 0; r < 6; r++){ AL2S[r] = ALB + o2; o2 += (size_t)Nt[rs[r]]; }
      for (int r = 0; r < 6; r++){ AL2D[r] = ALB + o2; o2 += (size_t)Nt[rd[r]]; } }

    CsrArgs ca;
    for (int r = 0; r < 6; r++){
        ca.src[r] = ep[r]; ca.dst[r] = ep[r] + Ecnt[r];
        ca.ecnt[r] = Ecnt[r]; ca.eoff[r] = eOff[r]; ca.nd[r] = Nt[rd[r]];
    }

    // ---- init: dtype detect + zero CNT/POS (single dispatch) ----
    init_k<<<64, 256, 0, stream>>>((const unsigned short*)d_in[0], FLAG, CNT, 12*OFFSTR);

    // ---- P1 ----
    P1Args p1;
    p1.ca = ca;
    p1.W1 = W1; p1.as1 = as1; p1.ad1 = ad1; p1.W2 = W2; p1.as2 = as2; p1.ad2 = ad2;
    p1.b1 = b1; p1.b2 = b2;
    p1.WA1S = WA1S; p1.WA1D = WA1D; p1.WA2S = WA2S; p1.WA2D = WA2D;
    p1.BIAS1 = BIAS1; p1.BIAS2 = BIAS2;
    p1.W1T = W1T; p1.W2T = W2T; p1.CNT = CNT;
    int nTw1 = cdiv(6LL*128*256, 256), nTw2 = cdiv(6LL*256*64, 256);
    p1.eTw1 = nTw1; p1.eTw2 = nTw1 + nTw2;
    p1.eWa1 = p1.eTw2 + 12; p1.eWa2 = p1.eWa1 + 6; p1.eBias = p1.eWa2 + 3;
    int cntBlk = 0;
    for (int r = 0; r < 6; r++){ p1.nbCnt[r] = cdiv(Ecnt[r], 256); cntBlk += p1.nbCnt[r]; }
    p1_k<<<p1.eBias + cntBlk, 256, 0, stream>>>(p1, FLAG);

    // ---- parallel scan (3 phases) ----
    ScanArgs sa;
    int scBlk = 0;
    for (int r = 0; r < 6; r++){
        sa.start[r] = scBlk;
        sa.nd[r] = Nt[rd[r]];
        sa.nch[r] = cdiv(Nt[rd[r]], 1024);
        scBlk += sa.nch[r];
    }
    scan_a<<<scBlk, 1024, 0, stream>>>(sa, CNT, OFF, CHT);
    scan_b<<<1, 64, 0, stream>>>(sa, CHT);
    scan_c<<<scBlk, 1024, 0, stream>>>(sa, OFF, CHT);

    // ---- P2 ----
    P2ArgsFix q2;
    q2.p.ca = ca; q2.p.OFF = OFF; q2.p.POS = POS; q2.p.SRCS = SRCS;
    int totBlk1 = 0;
    for (int r = 0; r < 6; r++){
        q2.p.g1.A[r] = x[rs[r]]; q2.p.g1.bOff[r] = (unsigned long long)r*256*128;
        q2.p.g1.cOff[r] = hs1off[r]; q2.p.g1.M[r] = Nt[rs[r]];
        q2.p.g1.nblk[r] = cdiv(Nt[rs[r]], 64); totBlk1 += q2.p.g1.nblk[r];
        q2.p.nbCnt[r] = p1.nbCnt[r];
    }
    for (int t = 0; t < 3; t++){
        q2.p.a1.x[t] = x[t]; q2.p.a1.nt[t] = Nt[t];
        q2.p.nbAl[t] = cdiv(Nt[t], 256);
        for (int j = 0; j < 2; j++){
            q2.p.a1.wa[t][j]   = WA1S + srel[t][j]*512;  q2.p.a1.out[t][j]   = AL1S[srel[t][j]];
            q2.p.a1.wa[t][j+2] = WA1D + drel[t][j]*512;  q2.p.a1.out[t][j+2] = AL1D[drel[t][j]];
        }
    }
    q2.p.eFill = cntBlk; q2.p.eGemm = cntBlk + 4*totBlk1;
    q2.W1T = W1T; q2.HS1 = (bf16*)HS1u;
    int nAl1 = q2.p.nbAl[0] + q2.p.nbAl[1] + q2.p.nbAl[2];
    p2_kf<<<q2.p.eGemm + nAl1, 256, 0, stream>>>(q2, FLAG);

    // ---- gat_l1 ----
    GatArgs gl1;
    for (int t = 0; t < 3; t++)
        for (int a = 0; a < 2; a++){
            int r = drel[t][a];
            gl1.srcs[t][a] = SRCS + eOff[r]; gl1.off[t][a] = OFF + r*OFFSTR;
            gl1.als[t][a] = AL1S[r]; gl1.ald[t][a] = AL1D[r];
            gl1.hs[t][a] = HS1u + hs1off[r];
        }
    gat_l1<<<cdiv(NTOT, 4), 256, 0, stream>>>(gl1, BIAS1, X2Bu);

    // ---- P3 ----
    P3ArgsFix q3;
    int totBlk2 = 0;
    for (int r = 0; r < 6; r++){
        q3.p.g2.A[r] = X2Bu + (size_t)accRow[rs[r]]*256;
        q3.p.g2.bOff[r] = (unsigned long long)r*64*256;
        q3.p.g2.cOff[r] = hs2off[r]; q3.p.g2.M[r] = Nt[rs[r]];
        q3.p.g2.nblk[r] = cdiv(Nt[rs[r]], 64); totBlk2 += q3.p.g2.nblk[r];
    }
    for (int t = 0; t < 3; t++){
        q3.p.a2.x[t] = X2Bu + (size_t)accRow[t]*256; q3.p.a2.nt[t] = Nt[t];
        q3.p.nbAl[t] = cdiv(Nt[t], 256);
        for (int j = 0; j < 2; j++){
            q3.p.a2.wa[t][j]   = WA2S + srel[t][j]*256;  q3.p.a2.out[t][j]   = AL2S[srel[t][j]];
            q3.p.a2.wa[t][j+2] = WA2D + drel[t][j]*256;  q3.p.a2.out[t][j+2] = AL2D[drel[t][j]];
        }
    }
    q3.p.eAl2 = q3.p.nbAl[0] + q3.p.nbAl[1] + q3.p.nbAl[2];
    q3.W2T = W2T; q3.HS2 = (bf16*)HS2u;
    p3_kf<<<q3.p.eAl2 + totBlk2, 256, 0, stream>>>(q3);

    // ---- gat_l2 ----
    GatArgs gl2;
    for (int t = 0; t < 3; t++)
        for (int a = 0; a < 2; a++){
            int r = drel[t][a];
            gl2.srcs[t][a] = SRCS + eOff[r]; gl2.off[t][a] = OFF + r*OFFSTR;
            gl2.als[t][a] = AL2S[r]; gl2.ald[t][a] = AL2D[r];
            gl2.hs[t][a] = HS2u + hs2off[r];
        }
    gat_l2<<<cdiv(NTOT, 4), 256, 0, stream>>>(gl2, BIAS2, d_out, FLAG);
}

// Round 13
// 547.260 us; speedup vs baseline: 1.3962x; 1.1100x over previous
//
#include <hip/hip_runtime.h>
#include <hip/hip_bf16.h>
#include <math.h>

#define NCIRC 40000
#define NMI   15000
#define NDIS  8000
#define NTOT  (NCIRC + NMI + NDIS)
#define OFFSTR 40064

typedef __hip_bfloat16 bf16;
typedef __attribute__((ext_vector_type(8))) short short8;
typedef __attribute__((ext_vector_type(4))) float f32x4;
typedef __attribute__((ext_vector_type(8))) unsigned short us8v;

static __device__ __forceinline__ float us2f(unsigned short u){ return __uint_as_float(((unsigned)u) << 16); }
static __device__ __forceinline__ unsigned short f2bu(float v){
    bf16 t = __float2bfloat16(v);
    return *reinterpret_cast<unsigned short*>(&t);
}
static __device__ __forceinline__ float ldx(const void* p, size_t i, int f32){
    return f32 ? ((const float*)p)[i] : __bfloat162float(((const bf16*)p)[i]);
}
static inline unsigned cdiv(long long a, long long b){ return (unsigned)((a + b - 1) / b); }

// ---------- arg structs ----------
struct CsrArgs {
    const int* src[6]; const int* dst[6];
    int ecnt[6]; int eoff[6]; int nd[6];
};
struct ScanArgs { int start[6]; int nch[6]; int nd[6]; };
struct Al1Args { const void* x[3]; const float* wa[3][4]; float* out[3][4]; int nt[3]; };
struct GemmArgs { const void* A[6]; unsigned long long bOff[6]; unsigned long long cOff[6];
                  int M[6]; int nblk[6]; };
struct GatArgs {
    const unsigned short* srcs[3][2]; const int* off[3][2];
    const int* cnt[3][2]; const int* cht[3][2];
    const float* als[3][2]; const float* ald[3][2];
    const unsigned short* hs[3][2];
    const float* wa2[3][4];    // l1 only
    float* al2o[3][4];         // l1 only (MUST NOT alias layer-1 logits!)
};
struct P1Args {
    CsrArgs ca;
    const void *W1, *as1, *ad1, *W2, *as2, *ad2, *b1, *b2;
    float *WA1S, *WA1D, *WA2S, *WA2D, *BIAS1, *BIAS2;
    bf16 *W1T, *W2T;
    int *CNT; unsigned short* EPOS;
    int eTw1, eTw2, eWa1, eWa2, eBias;
    int nbCnt[6];
};
struct P2Args {
    CsrArgs ca;
    const int* OFF; const int* CHT; const unsigned short* EPOS; unsigned short* SRCS;
    GemmArgs g1;
    Al1Args a1;
    int eFill, eGemm;
    int nbCnt[6];
    int nbAl[3];
};
struct P2ArgsFix { P2Args p; const bf16* W1T; bf16* HS1; };

// ---------- init ----------
__global__ void init_k(const unsigned short* __restrict__ u, int* __restrict__ flag,
                       int* __restrict__ zbase, int zcount){
    if (blockIdx.x == 0){
        __shared__ int sbad;
        if (threadIdx.x == 0) sbad = 0;
        __syncthreads();
        int bad = 0;
        for (int i = threadIdx.x; i < 4096; i += 256){
            int e = (u[i] >> 7) & 0xFF;
            if (e >= 0x90) bad = 1;
        }
        if (bad) atomicOr(&sbad, 1);
        __syncthreads();
        if (threadIdx.x == 0) *flag = sbad;
    } else {
        for (int i = (blockIdx.x - 1)*256 + threadIdx.x; i < zcount; i += 63*256)
            zbase[i] = 0;
    }
}

// ---------- device bodies ----------
static __device__ __forceinline__ void tw_body(const void* W, int f32, bf16* WT,
                                               int Kd, int Nd, int nrel, int blk){
    long long idx = (long long)blk * 256 + threadIdx.x;
    long long tot = (long long)nrel * Kd * Nd;
    if (idx >= tot) return;
    int per = Kd * Nd;
    int r = (int)(idx / per);
    int rem = (int)(idx % per);
    int n = rem / Kd, k = rem % Kd;
    float v = ldx(W, (size_t)r*per + (size_t)k*Nd + n, f32);
    WT[idx] = __float2bfloat16(v);
}

static __device__ __forceinline__ void wa1_body(const void* W1, const void* as1, const void* ad1,
                                                int f32, float* wa_s, float* wa_d, int blk){
    int r = blk >> 1;
    int t = (blk & 1)*256 + threadIdx.x;
    int f = t >> 2, h = t & 3;
    size_t wb = (size_t)r*128*256 + (size_t)f*256 + h*64;
    size_t ab = (size_t)r*256 + h*64;
    float ss = 0.f, sd = 0.f;
    for (int c = 0; c < 64; c++){
        float w = ldx(W1, wb + c, f32);
        ss += w * ldx(as1, ab + c, f32);
        sd += w * ldx(ad1, ab + c, f32);
    }
    wa_s[r*512 + t] = ss; wa_d[r*512 + t] = sd;
}

static __device__ __forceinline__ void wa2_body(const void* W2, const void* as2, const void* ad2,
                                                int f32, float* wa_s, float* wa_d, int r){
    int f = threadIdx.x;
    size_t wb = (size_t)r*256*64 + (size_t)f*64;
    float ss = 0.f, sd = 0.f;
    for (int c = 0; c < 64; c++){
        float w = ldx(W2, wb + c, f32);
        ss += w * ldx(as2, (size_t)r*64 + c, f32);
        sd += w * ldx(ad2, (size_t)r*64 + c, f32);
    }
    wa_s[r*256 + f] = ss; wa_d[r*256 + f] = sd;
}

static __device__ __forceinline__ void bias_body(const void* b1, const void* b2, int f32,
                                                 float* BIAS1, float* BIAS2, int t){
    const int relA[3] = {3, 0, 1};
    const int relB[3] = {5, 4, 2};
    int c = threadIdx.x;
    BIAS1[t*256 + c] = 0.5f*(ldx(b1, relA[t]*256 + c, f32) + ldx(b1, relB[t]*256 + c, f32));
    if (c < 64)
        BIAS2[t*64 + c] = 0.5f*(ldx(b2, relA[t]*64 + c, f32) + ldx(b2, relB[t]*64 + c, f32));
}

static __device__ void al1_body(const Al1Args& a, int f32, int t, int blk, float (*swa)[512]){
    int N = a.nt[t];
    for (int i = threadIdx.x; i < 2048; i += 256) swa[i >> 9][i & 511] = a.wa[t][i >> 9][i & 511];
    __syncthreads();
    int n = blk * 256 + threadIdx.x;
    if (n >= N) return;
    float s[4][4] = {};
    if (f32){
        const float* xr = (const float*)a.x[t] + (size_t)n*128;
        for (int f = 0; f < 128; f++){
            float v = xr[f];
            #pragma unroll
            for (int j = 0; j < 4; j++){
                s[j][0] += v*swa[j][f*4+0]; s[j][1] += v*swa[j][f*4+1];
                s[j][2] += v*swa[j][f*4+2]; s[j][3] += v*swa[j][f*4+3];
            }
        }
    } else {
        const unsigned short* xr = (const unsigned short*)a.x[t] + (size_t)n*128;
        for (int f0 = 0; f0 < 128; f0 += 8){
            us8v v8 = *(const us8v*)(xr + f0);
            #pragma unroll
            for (int jj = 0; jj < 8; jj++){
                float v = us2f(v8[jj]); int f = f0 + jj;
                #pragma unroll
                for (int j = 0; j < 4; j++){
                    s[j][0] += v*swa[j][f*4+0]; s[j][1] += v*swa[j][f*4+1];
                    s[j][2] += v*swa[j][f*4+2]; s[j][3] += v*swa[j][f*4+3];
                }
            }
        }
    }
    #pragma unroll
    for (int j = 0; j < 4; j++)
        *(float4*)(a.out[t][j] + (size_t)n*4) = make_float4(s[j][0], s[j][1], s[j][2], s[j][3]);
}

static __device__ void gemm_body(const GemmArgs& ga, int af32, const bf16* WT,
                                 bf16* Cb, int N, int K, int nIdx, int yTot,
                                 unsigned short (*As)[40], unsigned short (*Bs)[40]){
    int y = yTot, r = 0;
    while (r < 5 && y >= ga.nblk[r]){ y -= ga.nblk[r]; r++; }
    int M = ga.M[r];
    int m0 = y * 64, n0 = nIdx * 64;
    const void* A = ga.A[r];
    const unsigned short* WTu = (const unsigned short*)WT + ga.bOff[r];
    bf16* C = Cb + ga.cOff[r];
    int tid = threadIdx.x;
    int w = tid >> 6, lane = tid & 63;
    int quad = lane >> 4, l16 = lane & 15;
    int srow = tid >> 2, skc = (tid & 3) * 8;
    f32x4 acc[4] = {};
    for (int k0 = 0; k0 < K; k0 += 32){
        {
            int gr = m0 + srow;
            us8v av;
            if (gr < M){
                if (af32){
                    const float* ap = (const float*)A + (size_t)gr*K + k0 + skc;
                    #pragma unroll
                    for (int j = 0; j < 8; j++) av[j] = f2bu(ap[j]);
                } else {
                    av = *(const us8v*)((const unsigned short*)A + (size_t)gr*K + k0 + skc);
                }
            } else {
                #pragma unroll
                for (int j = 0; j < 8; j++) av[j] = 0;
            }
            *(us8v*)&As[srow][skc] = av;
        }
        *(us8v*)&Bs[srow][skc] = *(const us8v*)(WTu + (size_t)(n0 + srow)*K + k0 + skc);
        __syncthreads();
        short8 af = *(const short8*)&As[w*16 + l16][quad*8];
        #pragma unroll
        for (int c = 0; c < 4; c++){
            short8 bfv = *(const short8*)&Bs[c*16 + l16][quad*8];
            acc[c] = __builtin_amdgcn_mfma_f32_16x16x32_bf16(af, bfv, acc[c], 0, 0, 0);
        }
        __syncthreads();
    }
    #pragma unroll
    for (int c = 0; c < 4; c++){
        #pragma unroll
        for (int i = 0; i < 4; i++){
            int m = m0 + w*16 + quad*4 + i;
            if (m < M) C[(size_t)m*N + n0 + c*16 + l16] = __float2bfloat16(acc[c][i]);
        }
    }
}

// ---------- P1 ----------
__global__ void p1_k(P1Args p, const int* __restrict__ flag){
    int bid = blockIdx.x;
    int f32 = *flag;
    if (bid < p.eTw1){
        tw_body(p.W1, f32, p.W1T, 128, 256, 6, bid);
    } else if (bid < p.eTw2){
        tw_body(p.W2, f32, p.W2T, 256, 64, 6, bid - p.eTw1);
    } else if (bid < p.eWa1){
        wa1_body(p.W1, p.as1, p.ad1, f32, p.WA1S, p.WA1D, bid - p.eTw2);
    } else if (bid < p.eWa2){
        wa2_body(p.W2, p.as2, p.ad2, f32, p.WA2S, p.WA2D, bid - p.eWa1);
    } else if (bid < p.eBias){
        bias_body(p.b1, p.b2, f32, p.BIAS1, p.BIAS2, bid - p.eWa2);
    } else {
        int b = bid - p.eBias, r = 0;
        while (r < 5 && b >= p.nbCnt[r]){ b -= p.nbCnt[r]; r++; }
        int e = b*256 + threadIdx.x;
        if (e < p.ca.ecnt[r]){
            int d = p.ca.dst[r][e];
            int pos = atomicAdd(&p.CNT[r*OFFSTR + d], 1);
            p.EPOS[p.ca.eoff[r] + e] = (unsigned short)pos;
        }
    }
}

// ---------- parallel scan ----------
__global__ void scan_a(ScanArgs s, const int* __restrict__ cnt, int* __restrict__ off,
                       int* __restrict__ CHT){
    int b = blockIdx.x, r = 0;
    while (r < 5 && b >= s.start[r+1]) r++;
    int chunk = b - s.start[r];
    int N = s.nd[r];
    int tid = threadIdx.x, lane = tid & 63, wv = tid >> 6;
    __shared__ int wsum[16];
    int i = chunk*1024 + tid;
    int v = (i < N) ? cnt[r*OFFSTR + i] : 0;
    int x = v;
    #pragma unroll
    for (int d = 1; d < 64; d <<= 1){
        int y = __shfl_up(x, d, 64);
        if (lane >= d) x += y;
    }
    if (lane == 63) wsum[wv] = x;
    __syncthreads();
    if (tid == 0){
        int acc = 0;
        #pragma unroll
        for (int k = 0; k < 16; k++){ acc += wsum[k]; wsum[k] = acc; }
    }
    __syncthreads();
    int incl = x + ((wv == 0) ? 0 : wsum[wv - 1]);
    if (i < N) off[r*OFFSTR + i] = incl - v;          // chunk-local exclusive
    if (tid == 1023) CHT[r*64 + chunk] = incl;        // chunk total
}

__global__ void scan_b(ScanArgs s, int* __restrict__ CHT){
    int r = threadIdx.x;
    if (r < 6){
        int acc = 0;
        for (int c = 0; c < s.nch[r]; c++){
            int v = CHT[r*64 + c];
            CHT[r*64 + c] = acc;
            acc += v;
        }
    }
}

// ---------- P2: fill (atomic-free) + gemm L1 + al1 ----------
__global__ void p2_kf(P2ArgsFix q, const int* __restrict__ flag){
    __shared__ __align__(16) char smem[10240];
    P2Args& p = q.p;
    int bid = blockIdx.x;
    if (bid < p.eFill){
        int b = bid, r = 0;
        while (r < 5 && b >= p.nbCnt[r]){ b -= p.nbCnt[r]; r++; }
        int e = b*256 + threadIdx.x;
        if (e < p.ca.ecnt[r]){
            int d = p.ca.dst[r][e];
            int beg = p.OFF[r*OFFSTR + d] + p.CHT[r*64 + (d >> 10)];
            p.SRCS[p.ca.eoff[r] + beg + p.EPOS[p.ca.eoff[r] + e]] =
                (unsigned short)p.ca.src[r][e];
        }
    } else if (bid < p.eGemm){
        int id = bid - p.eFill;
        int nIdx = id & 3, yTot = id >> 2;
        unsigned short (*As)[40] = (unsigned short(*)[40])smem;
        unsigned short (*Bs)[40] = (unsigned short(*)[40])(smem + 5120);
        gemm_body(p.g1, *flag, q.W1T, q.HS1, 256, 128, nIdx, yTot, As, Bs);
    } else {
        int b = bid - p.eGemm, t = 0;
        while (t < 2 && b >= p.nbAl[t]){ b -= p.nbAl[t]; t++; }
        al1_body(p.a1, *flag, t, b, (float(*)[512])smem);
    }
}

// ---------- gemm2 ----------
__global__ void gemm2_k(GemmArgs g2, const bf16* __restrict__ W2T, bf16* __restrict__ HS2){
    __shared__ __align__(16) char smem[10240];
    unsigned short (*As)[40] = (unsigned short(*)[40])smem;
    unsigned short (*Bs)[40] = (unsigned short(*)[40])(smem + 5120);
    gemm_body(g2, 0, W2T, HS2, 64, 256, 0, blockIdx.x, As, Bs);
}

// ---------- layer-1 gather + fused ELU + fused al2 logits ----------
__global__ void gat_l1(GatArgs g, const float* __restrict__ BIAS1,
                       unsigned short* __restrict__ X2B){
    int gw = blockIdx.x * 4 + (threadIdx.x >> 6);
    if (gw >= NTOT) return;
    int t, w;
    if (gw < NCIRC){ t = 0; w = gw; }
    else if (gw < NCIRC + NMI){ t = 1; w = gw - NCIRC; }
    else { t = 2; w = gw - NCIRC - NMI; }
    int lane = threadIdx.x & 63;
    int hw = lane >> 5, l32 = lane & 31;
    int h = l32 >> 3;
    float fT[8] = {0.f,0.f,0.f,0.f,0.f,0.f,0.f,0.f};
    #pragma unroll
    for (int a = 0; a < 2; a++){
        const float* als = g.als[t][a];
        const unsigned short* srcs = g.srcs[t][a];
        const unsigned short* Hu = g.hs[t][a];
        float aldv = g.ald[t][a][(size_t)w*4 + h];
        int beg = g.off[t][a][w] + g.cht[t][a][w >> 10];
        int end = beg + g.cnt[t][a][w];
        float fa[8] = {0.f,0.f,0.f,0.f,0.f,0.f,0.f,0.f};
        float den = 0.f;
        int i = beg + hw;
        for (; i + 6 < end; i += 8){
            int s0 = srcs[i], s1 = srcs[i+2], s2 = srcs[i+4], s3 = srcs[i+6];
            us8v v0 = *(const us8v*)(Hu + (size_t)s0*256 + l32*8);
            us8v v1 = *(const us8v*)(Hu + (size_t)s1*256 + l32*8);
            us8v v2 = *(const us8v*)(Hu + (size_t)s2*256 + l32*8);
            us8v v3 = *(const us8v*)(Hu + (size_t)s3*256 + l32*8);
            float x0 = als[(size_t)s0*4 + h] + aldv;
            float x1 = als[(size_t)s1*4 + h] + aldv;
            float x2 = als[(size_t)s2*4 + h] + aldv;
            float x3 = als[(size_t)s3*4 + h] + aldv;
            float e0 = __expf(x0 > 0.f ? x0 : 0.2f*x0);
            float e1 = __expf(x1 > 0.f ? x1 : 0.2f*x1);
            float e2 = __expf(x2 > 0.f ? x2 : 0.2f*x2);
            float e3 = __expf(x3 > 0.f ? x3 : 0.2f*x3);
            den += e0 + e1 + e2 + e3;
            #pragma unroll
            for (int k = 0; k < 8; k++)
                fa[k] += e0*us2f(v0[k]) + e1*us2f(v1[k]) + e2*us2f(v2[k]) + e3*us2f(v3[k]);
        }
        for (; i < end; i += 2){
            int s = srcs[i];
            us8v v = *(const us8v*)(Hu + (size_t)s*256 + l32*8);
            float xv = als[(size_t)s*4 + h] + aldv;
            float e = __expf(xv > 0.f ? xv : 0.2f*xv);
            den += e;
            #pragma unroll
            for (int k = 0; k < 8; k++) fa[k] += e*us2f(v[k]);
        }
        den += __shfl_xor(den, 32, 64);
        float inv = 1.0f / (den + 1e-16f);
        #pragma unroll
        for (int k = 0; k < 8; k++) fT[k] += fa[k]*inv;
    }
    #pragma unroll
    for (int k = 0; k < 8; k++) fT[k] += __shfl_xor(fT[k], 32, 64);
    if (hw == 0){
        const float* bp = BIAS1 + t*256 + l32*8;
        float v[8];
        us8v st;
        #pragma unroll
        for (int k = 0; k < 8; k++){
            float vv = fT[k]*0.5f + bp[k];
            vv = vv > 0.f ? vv : (__expf(vv) - 1.f);
            v[k] = vv;
            st[k] = f2bu(vv);
        }
        *(us8v*)(X2B + (size_t)gw*256 + l32*8) = st;
        // fused layer-2 logits (AL2 buffers are DISJOINT from AL1 - see host layout)
        float s0 = 0.f, s1 = 0.f, s2 = 0.f, s3 = 0.f;
        const float* w0 = g.wa2[t][0] + l32*8;
        const float* w1 = g.wa2[t][1] + l32*8;
        const float* w2 = g.wa2[t][2] + l32*8;
        const float* w3 = g.wa2[t][3] + l32*8;
        #pragma unroll
        for (int k = 0; k < 8; k++){
            s0 += v[k]*w0[k]; s1 += v[k]*w1[k]; s2 += v[k]*w2[k]; s3 += v[k]*w3[k];
        }
        #pragma unroll
        for (int mk = 16; mk > 0; mk >>= 1){
            s0 += __shfl_xor(s0, mk, 64); s1 += __shfl_xor(s1, mk, 64);
            s2 += __shfl_xor(s2, mk, 64); s3 += __shfl_xor(s3, mk, 64);
        }
        if (l32 == 0){
            g.al2o[t][0][w] = s0; g.al2o[t][1][w] = s1;
            g.al2o[t][2][w] = s2; g.al2o[t][3][w] = s3;
        }
    }
}

// ---------- layer-2 gather: one-pass, quarter-wave, fused finalize ----------
__global__ void gat_l2(GatArgs g, const float* __restrict__ BIAS2,
                       void* __restrict__ out, const int* __restrict__ flag){
    int gw = blockIdx.x * 4 + (threadIdx.x >> 6);
    if (gw >= NTOT) return;
    int t, w;
    if (gw < NCIRC){ t = 0; w = gw; }
    else if (gw < NCIRC + NMI){ t = 1; w = gw - NCIRC; }
    else { t = 2; w = gw - NCIRC - NMI; }
    int lane = threadIdx.x & 63;
    int qw = lane >> 4, l16 = lane & 15;
    float fT[4] = {0.f,0.f,0.f,0.f};
    #pragma unroll
    for (int a = 0; a < 2; a++){
        const float* als = g.als[t][a];
        const unsigned short* srcs = g.srcs[t][a];
        const unsigned short* Hu = g.hs[t][a];
        float aldv = g.ald[t][a][w];
        int beg = g.off[t][a][w] + g.cht[t][a][w >> 10];
        int end = beg + g.cnt[t][a][w];
        float fa[4] = {0.f,0.f,0.f,0.f};
        float den = 0.f;
        int i = beg + qw;
        for (; i + 12 < end; i += 16){
            int s0 = srcs[i], s1 = srcs[i+4], s2 = srcs[i+8], s3 = srcs[i+12];
            ushort4 v0 = *(const ushort4*)(Hu + (size_t)s0*64 + l16*4);
            ushort4 v1 = *(const ushort4*)(Hu + (size_t)s1*64 + l16*4);
            ushort4 v2 = *(const ushort4*)(Hu + (size_t)s2*64 + l16*4);
            ushort4 v3 = *(const ushort4*)(Hu + (size_t)s3*64 + l16*4);
            float x0 = als[s0] + aldv, x1 = als[s1] + aldv;
            float x2 = als[s2] + aldv, x3 = als[s3] + aldv;
            float e0 = __expf(x0 > 0.f ? x0 : 0.2f*x0);
            float e1 = __expf(x1 > 0.f ? x1 : 0.2f*x1);
            float e2 = __expf(x2 > 0.f ? x2 : 0.2f*x2);
            float e3 = __expf(x3 > 0.f ? x3 : 0.2f*x3);
            den += e0 + e1 + e2 + e3;
            fa[0] += e0*us2f(v0.x) + e1*us2f(v1.x) + e2*us2f(v2.x) + e3*us2f(v3.x);
            fa[1] += e0*us2f(v0.y) + e1*us2f(v1.y) + e2*us2f(v2.y) + e3*us2f(v3.y);
            fa[2] += e0*us2f(v0.z) + e1*us2f(v1.z) + e2*us2f(v2.z) + e3*us2f(v3.z);
            fa[3] += e0*us2f(v0.w) + e1*us2f(v1.w) + e2*us2f(v2.w) + e3*us2f(v3.w);
        }
        for (; i < end; i += 4){
            int s = srcs[i];
            ushort4 v = *(const ushort4*)(Hu + (size_t)s*64 + l16*4);
            float xv = als[s] + aldv;
            float e = __expf(xv > 0.f ? xv : 0.2f*xv);
            den += e;
            fa[0] += e*us2f(v.x); fa[1] += e*us2f(v.y);
            fa[2] += e*us2f(v.z); fa[3] += e*us2f(v.w);
        }
        den += __shfl_xor(den, 32, 64);
        den += __shfl_xor(den, 16, 64);
        float inv = 1.0f / (den + 1e-16f);
        #pragma unroll
        for (int k = 0; k < 4; k++) fT[k] += fa[k]*inv;
    }
    #pragma unroll
    for (int k = 0; k < 4; k++){
        fT[k] += __shfl_xor(fT[k], 32, 64);
        fT[k] += __shfl_xor(fT[k], 16, 64);
    }
    const float* bp = BIAS2 + t*64 + l16*4;
    float v0 = fT[0]*0.5f + bp[0];
    float v1 = fT[1]*0.5f + bp[1];
    float v2 = fT[2]*0.5f + bp[2];
    float v3 = fT[3]*0.5f + bp[3];
    float ss = v0*v0 + v1*v1 + v2*v2 + v3*v3;
    #pragma unroll
    for (int mk = 8; mk > 0; mk >>= 1) ss += __shfl_xor(ss, mk, 64);
    float nrm = sqrtf(ss);
    nrm = nrm > 1e-12f ? nrm : 1e-12f;
    float inv_n = 1.0f / nrm;
    if (qw == 0){
        size_t base = (size_t)gw*64 + l16*4;
        if (*flag){
            *(float4*)((float*)out + base) = make_float4(v0*inv_n, v1*inv_n, v2*inv_n, v3*inv_n);
        } else {
            ushort4 st;
            st.x = f2bu(v0*inv_n); st.y = f2bu(v1*inv_n);
            st.z = f2bu(v2*inv_n); st.w = f2bu(v3*inv_n);
            *(ushort4*)((unsigned short*)out + base) = st;
        }
    }
}

// ---------- host ----------
extern "C" void kernel_launch(void* const* d_in, const int* in_sizes, int n_in,
                              void* d_out, int out_size, void* d_ws, size_t ws_size,
                              hipStream_t stream){
    const void* x[3] = {d_in[0], d_in[1], d_in[2]};
    const int Nt[3] = {NCIRC, NMI, NDIS};
    const int* ep[6]; int Ecnt[6];
    for (int r = 0; r < 6; r++){ ep[r] = (const int*)d_in[3 + r]; Ecnt[r] = in_sizes[3 + r] / 2; }
    const void* W1  = d_in[9];
    const void* as1 = d_in[10];
    const void* ad1 = d_in[11];
    const void* b1  = d_in[12];
    const void* W2  = d_in[13];
    const void* as2 = d_in[14];
    const void* ad2 = d_in[15];
    const void* b2  = d_in[16];

    const int rs[6] = {0, 1, 0, 1, 2, 2};
    const int rd[6] = {1, 2, 2, 0, 1, 0};
    const int srel[3][2] = {{0, 2}, {1, 3}, {4, 5}};
    const int drel[3][2] = {{3, 5}, {0, 4}, {1, 2}};
    const int accRow[3] = {0, NCIRC, NCIRC + NMI};

    // ---- workspace layout ----
    // ALB: [0, 1,008,000) = AL1S/AL1D (layer-1 logits)
    //      [1,008,000, 1,260,000) = AL2S/AL2D (layer-2 logits) -- DISJOINT (R12 bug fix)
    float* ws    = (float*)d_ws;
    int*   FLAG  = (int*)ws;
    float* WA1S  = ws + 16;
    float* WA1D  = WA1S + 6*512;
    float* WA2S  = WA1D + 6*512;
    float* WA2D  = WA2S + 6*256;
    float* BIAS1 = WA2D + 6*256;
    float* BIAS2 = BIAS1 + 768;
    float* ALB   = BIAS2 + 192;                                 // 1,260,000 floats
    unsigned short* HS1u = (unsigned short*)(ALB + 1260000);
    unsigned short* HS2u = HS1u + 32256000;
    unsigned short* X2Bu = HS2u + 8064000;
    bf16*  W1T   = (bf16*)(X2Bu + 16128000);
    bf16*  W2T   = W1T + 6*256*128;
    int*   CNT   = (int*)(W2T + 6*64*256);
    int*   OFF   = CNT + 6*OFFSTR;
    int*   CHT   = OFF + 6*OFFSTR;                              // 6*64
    unsigned short* EPOS = (unsigned short*)(CHT + 6*64);       // 2,000,000
    unsigned short* SRCS = EPOS + 2000000;                      // 2,000,000

    int eOff[6]; int acc_e = 0;
    for (int r = 0; r < 6; r++){ eOff[r] = acc_e; acc_e += Ecnt[r]; }
    unsigned long long hs1off[6], hs2off[6];
    { unsigned long long o1 = 0, o2 = 0;
      for (int r = 0; r < 6; r++){ hs1off[r] = o1; o1 += (unsigned long long)Nt[rs[r]]*256;
                                   hs2off[r] = o2; o2 += (unsigned long long)Nt[rs[r]]*64; } }
    float *AL1S[6], *AL1D[6], *AL2S[6], *AL2D[6];
    { size_t o = 0;
      for (int r = 0; r < 6; r++){ AL1S[r] = ALB + o; o += (size_t)Nt[rs[r]]*4; }
      for (int r = 0; r < 6; r++){ AL1D[r] = ALB + o; o += (size_t)Nt[rd[r]]*4; }
      size_t o2 = 1008000;                                      // disjoint from AL1
      for (int r = 0; r < 6; r++){ AL2S[r] = ALB + o2; o2 += (size_t)Nt[rs[r]]; }
      for (int r = 0; r < 6; r++){ AL2D[r] = ALB + o2; o2 += (size_t)Nt[rd[r]]; } }

    CsrArgs ca;
    for (int r = 0; r < 6; r++){
        ca.src[r] = ep[r]; ca.dst[r] = ep[r] + Ecnt[r];
        ca.ecnt[r] = Ecnt[r]; ca.eoff[r] = eOff[r]; ca.nd[r] = Nt[rd[r]];
    }

    // ---- init ----
    init_k<<<64, 256, 0, stream>>>((const unsigned short*)d_in[0], FLAG, CNT, 6*OFFSTR);

    // ---- P1 ----
    P1Args p1;
    p1.ca = ca;
    p1.W1 = W1; p1.as1 = as1; p1.ad1 = ad1; p1.W2 = W2; p1.as2 = as2; p1.ad2 = ad2;
    p1.b1 = b1; p1.b2 = b2;
    p1.WA1S = WA1S; p1.WA1D = WA1D; p1.WA2S = WA2S; p1.WA2D = WA2D;
    p1.BIAS1 = BIAS1; p1.BIAS2 = BIAS2;
    p1.W1T = W1T; p1.W2T = W2T; p1.CNT = CNT; p1.EPOS = EPOS;
    int nTw1 = cdiv(6LL*128*256, 256), nTw2 = cdiv(6LL*256*64, 256);
    p1.eTw1 = nTw1; p1.eTw2 = nTw1 + nTw2;
    p1.eWa1 = p1.eTw2 + 12; p1.eWa2 = p1.eWa1 + 6; p1.eBias = p1.eWa2 + 3;
    int cntBlk = 0;
    for (int r = 0; r < 6; r++){ p1.nbCnt[r] = cdiv(Ecnt[r], 256); cntBlk += p1.nbCnt[r]; }
    p1_k<<<p1.eBias + cntBlk, 256, 0, stream>>>(p1, FLAG);

    // ---- scan (2 phases) ----
    ScanArgs sa;
    int scBlk = 0;
    for (int r = 0; r < 6; r++){
        sa.start[r] = scBlk;
        sa.nd[r] = Nt[rd[r]];
        sa.nch[r] = cdiv(Nt[rd[r]], 1024);
        scBlk += sa.nch[r];
    }
    scan_a<<<scBlk, 1024, 0, stream>>>(sa, CNT, OFF, CHT);
    scan_b<<<1, 64, 0, stream>>>(sa, CHT);

    // ---- P2 ----
    P2ArgsFix q2;
    q2.p.ca = ca; q2.p.OFF = OFF; q2.p.CHT = CHT; q2.p.EPOS = EPOS; q2.p.SRCS = SRCS;
    int totBlk1 = 0;
    for (int r = 0; r < 6; r++){
        q2.p.g1.A[r] = x[rs[r]]; q2.p.g1.bOff[r] = (unsigned long long)r*256*128;
        q2.p.g1.cOff[r] = hs1off[r]; q2.p.g1.M[r] = Nt[rs[r]];
        q2.p.g1.nblk[r] = cdiv(Nt[rs[r]], 64); totBlk1 += q2.p.g1.nblk[r];
        q2.p.nbCnt[r] = p1.nbCnt[r];
    }
    for (int t = 0; t < 3; t++){
        q2.p.a1.x[t] = x[t]; q2.p.a1.nt[t] = Nt[t];
        q2.p.nbAl[t] = cdiv(Nt[t], 256);
        for (int j = 0; j < 2; j++){
            q2.p.a1.wa[t][j]   = WA1S + srel[t][j]*512;  q2.p.a1.out[t][j]   = AL1S[srel[t][j]];
            q2.p.a1.wa[t][j+2] = WA1D + drel[t][j]*512;  q2.p.a1.out[t][j+2] = AL1D[drel[t][j]];
        }
    }
    q2.p.eFill = cntBlk; q2.p.eGemm = cntBlk + 4*totBlk1;
    q2.W1T = W1T; q2.HS1 = (bf16*)HS1u;
    int nAl1 = q2.p.nbAl[0] + q2.p.nbAl[1] + q2.p.nbAl[2];
    p2_kf<<<q2.p.eGemm + nAl1, 256, 0, stream>>>(q2, FLAG);

    // ---- gat_l1 ----
    GatArgs gl1;
    for (int t = 0; t < 3; t++){
        for (int a = 0; a < 2; a++){
            int r = drel[t][a];
            gl1.srcs[t][a] = SRCS + eOff[r]; gl1.off[t][a] = OFF + r*OFFSTR;
            gl1.cnt[t][a] = CNT + r*OFFSTR; gl1.cht[t][a] = CHT + r*64;
            gl1.als[t][a] = AL1S[r]; gl1.ald[t][a] = AL1D[r];
            gl1.hs[t][a] = HS1u + hs1off[r];
        }
        for (int j = 0; j < 2; j++){
            gl1.wa2[t][j]   = WA2S + srel[t][j]*256;  gl1.al2o[t][j]   = AL2S[srel[t][j]];
            gl1.wa2[t][j+2] = WA2D + drel[t][j]*256;  gl1.al2o[t][j+2] = AL2D[drel[t][j]];
        }
    }
    gat_l1<<<cdiv(NTOT, 4), 256, 0, stream>>>(gl1, BIAS1, X2Bu);

    // ---- gemm2 ----
    GemmArgs g2;
    int totBlk2 = 0;
    for (int r = 0; r < 6; r++){
        g2.A[r] = X2Bu + (size_t)accRow[rs[r]]*256;
        g2.bOff[r] = (unsigned long long)r*64*256;
        g2.cOff[r] = hs2off[r]; g2.M[r] = Nt[rs[r]];
        g2.nblk[r] = cdiv(Nt[rs[r]], 64); totBlk2 += g2.nblk[r];
    }
    gemm2_k<<<totBlk2, 256, 0, stream>>>(g2, W2T, (bf16*)HS2u);

    // ---- gat_l2 ----
    GatArgs gl2;
    for (int t = 0; t < 3; t++)
        for (int a = 0; a < 2; a++){
            int r = drel[t][a];
            gl2.srcs[t][a] = SRCS + eOff[r]; gl2.off[t][a] = OFF + r*OFFSTR;
            gl2.cnt[t][a] = CNT + r*OFFSTR; gl2.cht[t][a] = CHT + r*64;
            gl2.als[t][a] = AL2S[r]; gl2.ald[t][a] = AL2D[r];
            gl2.hs[t][a] = HS2u + hs2off[r];
        }
    gat_l2<<<cdiv(NTOT, 4), 256, 0, stream>>>(gl2, BIAS2, d_out, FLAG);
}